// Round 16
// baseline (332.344 us; speedup 1.0000x reference)
//
#include <hip/hip_runtime.h>
#include <hip/hip_bf16.h>

// Problem constants (reference setup_inputs)
#define NN   5000   // nodes
#define EDIM 64     // embedding dim
#define DINC 32     // DIN
#define BB   16     // batch
#define LAGN 12     // LAG
#define BC   512    // BB*DINC
#define KPAD 5120   // k-extent padded to 128-tile multiple (zeros in [5000,5120))

typedef __attribute__((ext_vector_type(8))) short short8;   // 8 bf16 = 4 VGPRs
typedef __attribute__((ext_vector_type(4))) float float4v;  // MFMA 16x16 C/D

static __device__ __forceinline__ ushort f2bf(float x) {
  __hip_bfloat16 h = __float2bfloat16(x);
  return *reinterpret_cast<ushort*>(&h);
}
static __device__ __forceinline__ float bf2f(ushort u) {
  unsigned int x = ((unsigned int)u) << 16;
  return __uint_as_float(x);
}
static __device__ __forceinline__ short8 cvt8(const float* p) {  // 8 floats -> bf16x8
  const float4 v0 = *(const float4*)p, v1 = *(const float4*)(p + 4);
  short8 r;
  r[0] = (short)f2bf(v0.x); r[1] = (short)f2bf(v0.y);
  r[2] = (short)f2bf(v0.z); r[3] = (short)f2bf(v0.w);
  r[4] = (short)f2bf(v1.x); r[5] = (short)f2bf(v1.y);
  r[6] = (short)f2bf(v1.z); r[7] = (short)f2bf(v1.w);
  return r;
}

// async global->LDS DMA, 16 B per lane; LDS dst is wave-uniform base + lane*16.
static __device__ __forceinline__ void gll16(const ushort* g, ushort* l) {
  __builtin_amdgcn_global_load_lds(
      (const __attribute__((address_space(1))) void*)g,
      (__attribute__((address_space(3))) void*)l, 16, 0, 0);
}

// P row m (bf16) lives at ushort offset m*10000 + (m&1)*16  -> 64B-aligned rows.
// Split-K partial slab z for row m: ushort offset m*10000 + 5160 + z*512.
// Softmax chunk partial sums fp32[8] for row m: ushort offset m*10000 + 9472
// (16B-aligned, 32 B; spare region [9256,10000) of each row; GEMM epilogue
// tops out at 9255). reduce_kernel sums the 8 and multiplies by reciprocal.

// ---------------------------------------------------------------------------
// K0: merged prep — transpose_xb | wt hi/lo transposed pools | emb hi/lo bf16.
// R20: wpool/wwin emitted TRANSPOSED + hi/lo bf16 (wtH/wtL[col'][64]) so the
// Wt/wwt GEMM runs on MFMA with the fused_A B-fragment read pattern.
// (xwc NOT here: its buffer overlays the A/P region — write after reduce2.)
// ---------------------------------------------------------------------------
__global__ __launch_bounds__(256) void prep_kernel(const float* __restrict__ x,
                                                   const float* __restrict__ wpool,
                                                   const float* __restrict__ wwin,
                                                   const float* __restrict__ emb,
                                                   ushort* __restrict__ XbT,
                                                   ushort* __restrict__ wtH,
                                                   ushort* __restrict__ wtL,
                                                   ushort* __restrict__ eH,
                                                   ushort* __restrict__ eL) {
  const int b = blockIdx.x, tid = threadIdx.x;
  if (b < 10240) {            // XbT[j][m] = bf16(x[j>>5][m][j&31]), zero pad m>=NN
    const int j = b / 20, m = (b - j * 20) * 256 + tid;
    const int bb = j >> 5, c = j & 31;
    ushort v = 0;
    if (m < NN) v = f2bf(x[((size_t)bb * NN + m) * DINC + c]);
    XbT[(size_t)j * KPAD + m] = v;
  } else if (b < 11008) {     // wpool -> wtH/wtL[col'][d], col' = o*96+kk*32+i
    const int t = (b - 10240) * 256 + tid;    // 768*256 = 3072*64
    const int col = t >> 6, d = t & 63;
    const int o = col / 96, r2 = col - o * 96, kk = r2 >> 5, i = r2 & 31;
    const float v = wpool[(size_t)d * 3072 + kk * 1024 + i * 32 + o];
    const ushort h = f2bf(v);
    wtH[t] = h;                               // t == col*64 + d exactly
    wtL[t] = f2bf(v - bf2f(h));
  } else if (b < 11136) {     // wwin -> wtH/wtL[3072+col''][d], col'' = o*16+i
    const int t = (b - 11008) * 256 + tid;    // 128*256 = 512*64
    const int col = t >> 6, d = t & 63;
    const int o = col >> 4, i = col & 15;
    const float v = wwin[(size_t)d * 512 + i * 32 + o];
    const ushort h = f2bf(v);
    wtH[196608 + t] = h;                      // 196608 = 3072*64
    wtL[196608 + t] = f2bf(v - bf2f(h));
  } else {                    // emb -> bf16 hi + bf16 residual, rows padded to 5120
    const int t = (b - 11136) * 256 + tid;    // 1280*256 = 5120*64
    const int row = t >> 6;
    float v = 0.f;
    if (row < NN) v = emb[t];                 // t == row*64 + col exactly
    const ushort h = f2bf(v);
    eH[t] = h;
    eL[t] = f2bf(v - bf2f(h));
  }
}

// ---------------------------------------------------------------------------
// K1: fused A + exp, MFMA, no fp32 A intermediate, DIAG-SHIFT (R12).
// Normalization is deferred to the reduce kernels; any per-row constant c_m
// cancels exactly in e/sum — c_m = diag |e_m|^2 bounds the exponent. Each
// chunk-block recomputes the IDENTICAL diag from identical fragments
// (deterministic FP) -> all chunk sums of a row share one shift.
// R18: LDS-STAGED B-SIDE with global_load_lds + LDS dbuf. R23 (verified,
// -8 us): 8-way column split (grid 1256, 5 tiles/block) fixes the 2-round
// quantization at 2 blocks/CU. Chunk sums -> fp32[8] at 9472+2*ch.
// Per tile: stage(t+1) || MFMA+exp -> barrier -> stores (R22 ordering).
// Grid 1256 = 157 row-groups x 8 chunks of 640 cols; 5 tiles of 128 cols.
// ---------------------------------------------------------------------------
__global__ __launch_bounds__(256) void fused_A_softmax_kernel(const ushort* __restrict__ eH,
                                                              const ushort* __restrict__ eL,
                                                              ushort* __restrict__ P,
                                                              ushort* __restrict__ scr) {
  __shared__ __align__(16) ushort Ls[32768];  // 64 KB: [2 bufs][H 8192 | L 8192]
  const int tid = threadIdx.x;
  const int w = tid >> 6, l = tid & 63;
  const int fm = l & 15, kq = l >> 4;
  const int rg = blockIdx.x >> 3, ch = blockIdx.x & 7;  // grid 1256
  const int row0 = rg * 32;                   // rows 0..5023
  const int cbase = ch * 640;
  __shared__ float redL[4][32];
  __shared__ float diagL[32];

  // staging decode (mfma_gemm pattern): call q covers tile-rows q*32+(tid>>3),
  // chunk slot tid&7 (XOR-swizzled); LDS dst = wave-uniform + lane*16.
  const int rstg = tid >> 3;            // 0..31
  const int slot = tid & 7;
  ushort* lH = Ls + tid * 8;            // + buf*16384 + q*2048
  ushort* lL = Ls + 8192 + tid * 8;

  auto stage = [&](int buf, int t) {
    const int c0 = cbase + t * 128;
#pragma unroll
    for (int q = 0; q < 4; ++q) {
      const int r = q * 32 + rstg;
      const int cg = slot ^ (r & 7);
      gll16(eH + (size_t)(c0 + r) * 64 + cg * 8, lH + buf * 16384 + q * 2048);
    }
#pragma unroll
    for (int q = 0; q < 4; ++q) {
      const int r = q * 32 + rstg;
      const int cg = slot ^ (r & 7);
      gll16(eL + (size_t)(c0 + r) * 64 + cg * 8, lL + buf * 16384 + q * 2048);
    }
  };

  // A-side fragments (32 rows), loaded once: frag row = fm, k-slot = s*4+kq
  short8 aH[2][2], aL[2][2];
#pragma unroll
  for (int mf = 0; mf < 2; ++mf)
#pragma unroll
    for (int s = 0; s < 2; ++s) {
      const size_t o = (size_t)(row0 + mf * 16 + fm) * 64 + (s * 4 + kq) * 8;
      aH[mf][s] = *(const short8*)(eH + o);
      aL[mf][s] = *(const short8*)(eL + o);
    }

  stage(0, 0);   // tile-0 DMAs in flight under the diag reduction below

  // Per-row diag |e_row|^2 from the fragments: lane covers 16 of 64 elems
  // (k-slots kq and 4+kq); butterfly over the kq lane bits (16, 32).
#pragma unroll
  for (int mf = 0; mf < 2; ++mf) {
    float p = 0.f;
#pragma unroll
    for (int s = 0; s < 2; ++s)
#pragma unroll
      for (int j = 0; j < 8; ++j) {
        const float v = bf2f((ushort)aH[mf][s][j]) + bf2f((ushort)aL[mf][s][j]);
        p = fmaf(v, v, p);
      }
    p += __shfl_xor(p, 16);
    p += __shfl_xor(p, 32);
    if (w == 0 && kq == 0) diagL[mf * 16 + fm] = p;   // row mf*16+fm
  }
  __syncthreads();   // diagL visible AND tile-0 DMAs drained (vmcnt(0))
  float shift[2][4];
#pragma unroll
  for (int mf = 0; mf < 2; ++mf)
#pragma unroll
    for (int r = 0; r < 4; ++r) shift[mf][r] = diagL[mf * 16 + kq * 4 + r];

  float rs[2][4] = {};
  ushort* prow[2][4];
#pragma unroll
  for (int mf = 0; mf < 2; ++mf)
#pragma unroll
    for (int r = 0; r < 4; ++r) {
      const int gm = row0 + mf * 16 + kq * 4 + r;
      prow[mf][r] = (gm < NN) ? (P + (size_t)gm * 10000 + (gm & 1) * 16) : scr;
    }

  int cur = 0;
  for (int t = 0; t < 5; ++t) {
    if (t < 4) stage(cur ^ 1, t + 1);   // issue tile t+1 DMAs (overlap below)
    const ushort* H = Ls + cur * 16384;
    const ushort* L = H + 8192;
    const int c0 = cbase + t * 128;
    float4v acc[2][2] = {};
#pragma unroll
    for (int s = 0; s < 2; ++s) {
      short8 bh[2], bl[2];
#pragma unroll
      for (int nf = 0; nf < 2; ++nf) {
        const int row = w * 32 + nf * 16 + fm;      // local col within tile
        const int sl = (s * 4 + kq) ^ (fm & 7);
        bh[nf] = *(const short8*)(H + row * 64 + sl * 8);
        bl[nf] = *(const short8*)(L + row * 64 + sl * 8);
      }
#pragma unroll
      for (int mf = 0; mf < 2; ++mf)
#pragma unroll
        for (int nf = 0; nf < 2; ++nf) {
          acc[mf][nf] = __builtin_amdgcn_mfma_f32_16x16x32_bf16(aL[mf][s], bh[nf], acc[mf][nf], 0, 0, 0);
          acc[mf][nf] = __builtin_amdgcn_mfma_f32_16x16x32_bf16(aH[mf][s], bl[nf], acc[mf][nf], 0, 0, 0);
          acc[mf][nf] = __builtin_amdgcn_mfma_f32_16x16x32_bf16(aH[mf][s], bh[nf], acc[mf][nf], 0, 0, 0);
        }
    }
    // exp/VALU epilogue BEFORE the barrier (covers the in-flight DMAs);
    // values parked in statically-indexed regs.
    ushort ev[2][2][4];
#pragma unroll
    for (int nf = 0; nf < 2; ++nf) {
      const int col = c0 + w * 32 + nf * 16 + fm;
      const bool ok = col < NN;               // k-pad cols [5000,5120) -> exact 0
#pragma unroll
      for (int mf = 0; mf < 2; ++mf)
#pragma unroll
        for (int r = 0; r < 4; ++r) {
          const float v = fmaxf(acc[mf][nf][r], 0.f);   // relu
          const float e = ok ? __expf(v - shift[mf][r]) : 0.f;
          rs[mf][r] += e;
          ev[nf][mf][r] = f2bf(e);
        }
    }
    __builtin_amdgcn_sched_barrier(0);  // pin the exp VALU before the barrier
    if (t < 4) __syncthreads();         // drains aged DMAs + PREV tile's stores
    // stores AFTER the barrier: their drain is deferred to the next barrier.
#pragma unroll
    for (int nf = 0; nf < 2; ++nf) {
      const int col = c0 + w * 32 + nf * 16 + fm;
#pragma unroll
      for (int mf = 0; mf < 2; ++mf)
#pragma unroll
        for (int r = 0; r < 4; ++r)
          prow[mf][r][col] = ev[nf][mf][r];
    }
    cur ^= 1;
  }

  // chunk sums: shfl over the 16 fm-lanes, LDS over the 4 waves, write fp32
  // at row spare offset 9472 + 2*ch (ch = 0..7).
#pragma unroll
  for (int mf = 0; mf < 2; ++mf)
#pragma unroll
    for (int r = 0; r < 4; ++r) {
      float v = rs[mf][r];
#pragma unroll
      for (int msk = 1; msk < 16; msk <<= 1) v += __shfl_xor(v, msk);
      rs[mf][r] = v;
    }
  __syncthreads();           // redL region reuse barrier (after compute loop)
  if (fm == 0) {
#pragma unroll
    for (int mf = 0; mf < 2; ++mf)
#pragma unroll
      for (int r = 0; r < 4; ++r) redL[w][mf * 16 + kq * 4 + r] = rs[mf][r];
  }
  __syncthreads();
  if (w == 0 && fm == 0) {
#pragma unroll
    for (int mf = 0; mf < 2; ++mf)
#pragma unroll
      for (int r = 0; r < 4; ++r) {
        const int mm = mf * 16 + kq * 4 + r;
        const int gm = row0 + mm;
        if (gm < NN) {
          const float tot = redL[0][mm] + redL[1][mm] + redL[2][mm] + redL[3][mm];
          *(float*)(P + (size_t)gm * 10000 + 9472 + 2 * ch) = tot;
        }
      }
  }
}

// ---------------------------------------------------------------------------
// K3/K5: bf16 MFMA GEMM. R24: BM=128, BN=64 (was 128) — OCCUPANCY FIX.
// R15 counters: 42.8 us, MfmaUtil 25%, occupancy 15% = the 2-phase template
// ceiling (626 TF ~ guide's 650-680) AND 2-blocks/CU quantization (1280
// blocks / 512 slots = 2.5 -> 3 lockstep rounds, ~17% waste). BN=64 halves
// LDS to 48 KB -> 3 blocks/CU (12 waves/CU): grid 2560 half-blocks / 768
// slots = 3.33 rounds of half-blocks ~ 1.67 full-round-equivalents, plus
// more cross-block barrier overlap. 256 thr = 4 waves (2x2 of 64x32, 16
// MFMAs/wave/iter, acc[4][2]). Split-K=8 (k-chunk 640 = 10 iters).
// Decode: yb = id>>6 (0..39, OUTER), xb = (id>>3)&7 (0..7), zb = id&7
// (= XCD; 64,8 both 0 mod 8). Per-XCD co-resident 12 yb x 8 xb: A 1.9 MB +
// B 0.64 MB < 4 MB L2 (R19 principle preserved).
// R13 pipeline: stage k+1 before compute k; ONE __syncthreads()/iter (its
// vmcnt(0) drain = the "tile landed" wait, after the MFMAs). R9 DMA
// locality: each wave-instr loads 8 ROWS x 128 B. Bank conflicts avoided by
// GLOBAL-side k-chunk XOR swizzle (lane fetches chunk slot^(row&7); frag
// reads slot (s*4+kq)^(fm&7)) — measured 0 conflicts.
// LDS layout: buf*12288 + [A 8192 | B 4096] ushorts (A 4 q-calls, B 2).
// ---------------------------------------------------------------------------
__global__ __launch_bounds__(256) void mfma_gemm_kernel(const ushort* __restrict__ Pm,
                                                        const ushort* __restrict__ Bt,
                                                        ushort* __restrict__ Pp) {
  __shared__ __align__(16) ushort Ls[24576];  // 48 KB: 2 bufs x (A 8192 + B 4096)
  const int tid = threadIdx.x;
  const int w = tid >> 6, l = tid & 63;
  const int fm = l & 15, kq = l >> 4;
  const int wm = w >> 1, wn = w & 1;    // 2x2 waves over (128 rows, 64 cols)
  const int id = blockIdx.x;            // 0..2559
  const int yb = id >> 6;               // row tile 0..39  (OUTER)
  const int xb = (id >> 3) & 7;         // col tile 0..7   (inner)
  const int zb = id & 7;                // k-chunk 0..7 (= XCD)
  const int row0 = yb * 128, col0 = xb * 64;
  const int kbase = zb * 640;
  // staging: call q covers rows q*32+(tid>>3), chunk slot tid&7 (XOR-swizzled)
  const int rstg = tid >> 3;            // 0..31
  const int slot = tid & 7;
  const ushort* gAq[4];
  const ushort* gBq[2];
#pragma unroll
  for (int q = 0; q < 4; ++q) {
    const int r = q * 32 + rstg;
    const int cg = slot ^ (r & 7);      // global k-chunk this lane fetches
    const int arow = row0 + r;
    gAq[q] = Pm + (size_t)arow * 10000 + (arow & 1) * 16 + kbase + cg * 8;
  }
#pragma unroll
  for (int q = 0; q < 2; ++q) {
    const int r = q * 32 + rstg;
    const int cg = slot ^ (r & 7);
    gBq[q] = Bt + (size_t)(col0 + r) * KPAD + kbase + cg * 8;
  }
  ushort* lA = Ls + tid * 8;            // + buf*12288 + q*2048 (row-major exact)
  ushort* lB = Ls + 8192 + tid * 8;
  float4v acc[4][2] = {};

  auto stage = [&](int buf) {
#pragma unroll
    for (int q = 0; q < 4; ++q) gll16(gAq[q], lA + buf * 12288 + q * 2048);
#pragma unroll
    for (int q = 0; q < 2; ++q) gll16(gBq[q], lB + buf * 12288 + q * 2048);
#pragma unroll
    for (int q = 0; q < 4; ++q) gAq[q] += 64;
#pragma unroll
    for (int q = 0; q < 2; ++q) gBq[q] += 64;
  };
  auto compute = [&](int buf) {
    const ushort* As = Ls + buf * 12288;
    const ushort* Bs = As + 8192;
#pragma unroll
    for (int s = 0; s < 2; ++s) {
      short8 a[4], b[2];
#pragma unroll
      for (int mt = 0; mt < 4; ++mt) {
        const int row = wm * 64 + mt * 16 + fm;
        const int sl = (s * 4 + kq) ^ (fm & 7);
        a[mt] = *(const short8*)(As + row * 64 + sl * 8);
      }
#pragma unroll
      for (int nt = 0; nt < 2; ++nt) {
        const int row = wn * 32 + nt * 16 + fm;
        const int sl = (s * 4 + kq) ^ (fm & 7);
        b[nt] = *(const short8*)(Bs + row * 64 + sl * 8);
      }
#pragma unroll
      for (int mt = 0; mt < 4; ++mt)
#pragma unroll
        for (int nt = 0; nt < 2; ++nt)
          acc[mt][nt] = __builtin_amdgcn_mfma_f32_16x16x32_bf16(a[mt], b[nt], acc[mt][nt], 0, 0, 0);
    }
  };

  stage(0);          // prologue: tile 0 -> buf 0
  __syncthreads();   // vmcnt(0) drain + barrier: buf0 ready
  int cur = 0;
  for (int kt = 0; kt < 9; ++kt) {
    stage(cur ^ 1);  // issue tile kt+1 DMAs (async, overlap with MFMAs below)
    compute(cur);
    __syncthreads(); // drains this iter's DMAs (tile kt+1 ready) + all waves
    cur ^= 1;        // done reading buf cur -> safe to overwrite next iter
  }
  compute(cur);      // last tile, no prefetch

  // epilogue: bf16 partials into the P rows' free halves
  const int cb = col0 + wn * 32 + fm;
  const int zoff = 5160 + zb * 512;
#pragma unroll
  for (int mt = 0; mt < 4; ++mt)
#pragma unroll
    for (int r = 0; r < 4; ++r) {
      const int gm = row0 + wm * 64 + mt * 16 + kq * 4 + r;
      if (gm < NN) {
        ushort* prow = Pp + (size_t)gm * 10000 + zoff + cb;
#pragma unroll
        for (int nt = 0; nt < 2; ++nt) prow[nt * 16] = f2bf(acc[mt][nt][r]);
      }
    }
}

// ---------------------------------------------------------------------------
// K4/K6: sum 8 bf16 split-K partials, SCALE by the row's deferred softmax
// inverse sum (1 / sum of the 8 fp32 chunk sums at P-row ushort offset 9472,
// two 16B-aligned float4s) -> Yf fp32 [5000][512]; optionally also Yt bf16
// [512][KPAD] (transposed, zero pad m in [5000,5120)). Grid (8,80).
// ---------------------------------------------------------------------------
__global__ __launch_bounds__(256) void reduce_kernel(const ushort* __restrict__ Pp,
                                                     float* __restrict__ Yf,
                                                     ushort* __restrict__ Yt,
                                                     int writeT) {
  const int m0 = blockIdx.y * 64, n0 = blockIdx.x * 64;
  __shared__ __align__(16) ushort Lt[64][80];  // [n][m]
  const int tid = threadIdx.x;
  const int mi = tid >> 4, nl4 = (tid & 15) << 2;
#pragma unroll
  for (int s = 0; s < 4; ++s) {
    const int m = m0 + mi + s * 16;
    float4 sum = make_float4(0.f, 0.f, 0.f, 0.f);
    if (m < NN) {
      const ushort* pr = Pp + (size_t)m * 10000 + 5160 + n0 + nl4;
#pragma unroll
      for (int z = 0; z < 8; ++z) {
        ushort4 u = *(const ushort4*)(pr + z * 512);
        sum.x += bf2f(u.x); sum.y += bf2f(u.y);
        sum.z += bf2f(u.z); sum.w += bf2f(u.w);
      }
      const float4 s4a = *(const float4*)(Pp + (size_t)m * 10000 + 9472);
      const float4 s4b = *(const float4*)(Pp + (size_t)m * 10000 + 9480);
      const float sc = 1.f / (s4a.x + s4a.y + s4a.z + s4a.w +
                              s4b.x + s4b.y + s4b.z + s4b.w);
      sum.x *= sc; sum.y *= sc; sum.z *= sc; sum.w *= sc;
      *(float4*)(Yf + (size_t)m * BC + n0 + nl4) = sum;
    }
    if (writeT) {
      const int ml = mi + s * 16;
      Lt[nl4 + 0][ml] = f2bf(sum.x);
      Lt[nl4 + 1][ml] = f2bf(sum.y);
      Lt[nl4 + 2][ml] = f2bf(sum.z);
      Lt[nl4 + 3][ml] = f2bf(sum.w);
    }
  }
  if (writeT) {
    __syncthreads();
#pragma unroll
    for (int i = 0; i < 2; ++i) {
      const int g = tid + i * 256;
      const int nl = g >> 3, gi = g & 7;
      *(uint4*)(Yt + (size_t)(n0 + nl) * KPAD + m0 + gi * 8) =
          *(const uint4*)(&Lt[nl][gi * 8]);
    }
  }
}

// ---------------------------------------------------------------------------
// K7: Wt/wwt via MFMA (R20/R21). A-frags built from the fp32 emb INPUT on
// the fly (hi/lo split, deterministic) — NOT from embH/embL, which overlay
// Y1f and are DEAD after reduce1. C[gm][col] = sum_d emb[gm][d]*wt[col][d],
// col in [0,3584): [0,3072) -> Wt (stride 3072), [3072,3584) -> wwt (512).
// Grid 157 x 14 col-chunks of 256 = 2198 blocks. B-frags direct from
// L2-resident wtH/wtL (448 KB each, untouched between prep and here).
// 48 MFMAs/block, 3-term hi/lo. Pad rows zero-guarded / store-guarded.
// ---------------------------------------------------------------------------
__global__ __launch_bounds__(256) void emb_wt_mfma_kernel(const float* __restrict__ emb,
                                                          const ushort* __restrict__ wtH,
                                                          const ushort* __restrict__ wtL,
                                                          ushort* __restrict__ Wt,
                                                          ushort* __restrict__ wwt) {
  const int tid = threadIdx.x;
  const int w = tid >> 6, l = tid & 63;
  const int fm = l & 15, kq = l >> 4;
  const int rg = blockIdx.x / 14, cc = blockIdx.x % 14;  // 157 x 14
  const int row0 = rg * 32;                   // rows 0..5023
  const int c0 = cc * 256 + w * 64;           // wave's col base in [0,3584)

  short8 aH[2][2], aL[2][2];
#pragma unroll
  for (int mf = 0; mf < 2; ++mf) {
    const int gr = row0 + mf * 16 + fm;
#pragma unroll
    for (int s = 0; s < 2; ++s) {
      short8 h = {}, lo = {};
      if (gr < NN) {
        const float* p = emb + (size_t)gr * EDIM + (s * 4 + kq) * 8;
        const float4 v0 = *(const float4*)p, v1 = *(const float4*)(p + 4);
        const float vv[8] = {v0.x, v0.y, v0.z, v0.w, v1.x, v1.y, v1.z, v1.w};
#pragma unroll
        for (int j = 0; j < 8; ++j) {
          const ushort hh = f2bf(vv[j]);
          h[j] = (short)hh;
          lo[j] = (short)f2bf(vv[j] - bf2f(hh));
        }
      }
      aH[mf][s] = h;
      aL[mf][s] = lo;
    }
  }

  float4v acc[2][4] = {};
#pragma unroll
  for (int s = 0; s < 2; ++s) {
    short8 bh[4], bl[4];
#pragma unroll
    for (int nf = 0; nf < 4; ++nf) {
      const size_t o = (size_t)(c0 + nf * 16 + fm) * 64 + (s * 4 + kq) * 8;
      bh[nf] = *(const short8*)(wtH + o);
      bl[nf] = *(const short8*)(wtL + o);
    }
#pragma unroll
    for (int mf = 0; mf < 2; ++mf)
#pragma unroll
      for (int nf = 0; nf < 4; ++nf) {
        acc[mf][nf] = __builtin_amdgcn_mfma_f32_16x16x32_bf16(aL[mf][s], bh[nf], acc[mf][nf], 0, 0, 0);
        acc[mf][nf] = __builtin_amdgcn_mfma_f32_16x16x32_bf16(aH[mf][s], bl[nf], acc[mf][nf], 0, 0, 0);
        acc[mf][nf] = __builtin_amdgcn_mfma_f32_16x16x32_bf16(aH[mf][s], bh[nf], acc[mf][nf], 0, 0, 0);
      }
  }
#pragma unroll
  for (int nf = 0; nf < 4; ++nf) {
    const int col = c0 + nf * 16 + fm;
#pragma unroll
    for (int mf = 0; mf < 2; ++mf)
#pragma unroll
      for (int r = 0; r < 4; ++r) {
        const int gm = row0 + mf * 16 + kq * 4 + r;
        if (gm < NN) {
          const ushort v = f2bf(acc[mf][nf][r]);
          if (col < 3072) Wt[(size_t)gm * 3072 + col] = v;
          else            wwt[(size_t)gm * 512 + (col - 3072)] = v;
        }
      }
  }
}

// ---------------------------------------------------------------------------
// K9: biasN fp32 [5000][64] = emb @ bias_pool.
// ---------------------------------------------------------------------------
__global__ __launch_bounds__(256) void emb_gemm_kernel(const float* __restrict__ Ae,
                                                       const float* __restrict__ Bw,
                                                       float* __restrict__ C,
                                                       int M, int Nc) {
  __shared__ float Aet[EDIM][33];
  __shared__ __align__(16) float Bs[EDIM][64];
  const int row0 = blockIdx.y * 32, col0 = blockIdx.x * 64;
  const int tid = threadIdx.x;
  for (int i = tid; i < 512; i += 256) {
    const int r = i >> 4, d4 = (i & 15) << 2;
    const int gm = row0 + r;
    float4 v = make_float4(0.f, 0.f, 0.f, 0.f);
    if (gm < M) v = *(const float4*)(Ae + (size_t)gm * EDIM + d4);
    Aet[d4 + 0][r] = v.x; Aet[d4 + 1][r] = v.y; Aet[d4 + 2][r] = v.z; Aet[d4 + 3][r] = v.w;
  }
  for (int i = tid; i < 1024; i += 256) {
    const int br = i >> 4, bc = (i & 15) << 2;
    if (bc < Nc) *(float4*)&Bs[br][bc] = *(const float4*)(Bw + (size_t)br * Nc + bc);
  }
  __syncthreads();
  const int ty = tid >> 4, tx = tid & 15;
  float acc[2][4] = {};
#pragma unroll 8
  for (int d = 0; d < EDIM; ++d) {
    const float a0 = Aet[d][ty * 2], a1 = Aet[d][ty * 2 + 1];
    const float4 b4 = *(const float4*)&Bs[d][tx << 2];
    acc[0][0] = fmaf(a0, b4.x, acc[0][0]); acc[0][1] = fmaf(a0, b4.y, acc[0][1]);
    acc[0][2] = fmaf(a0, b4.z, acc[0][2]); acc[0][3] = fmaf(a0, b4.w, acc[0][3]);
    acc[1][0] = fmaf(a1, b4.x, acc[1][0]); acc[1][1] = fmaf(a1, b4.y, acc[1][1]);
    acc[1][2] = fmaf(a1, b4.z, acc[1][2]); acc[1][3] = fmaf(a1, b4.w, acc[1][3]);
  }
#pragma unroll
  for (int r = 0; r < 2; ++r) {
    const int gm = row0 + ty * 2 + r;
    if (gm >= M) continue;
    float4 o;
    o.x = acc[r][0]; o.y = acc[r][1]; o.z = acc[r][2]; o.w = acc[r][3];
    *(float4*)(C + (size_t)gm * Nc + col0 + (tx << 2)) = o;
  }
}

// ---------------------------------------------------------------------------
// K10: xwc[b, n, i] = sum_t T[t] * x_window[b, t, n, i]
// (launched AFTER reduce2: xwc buffer overlays the dead A/P region)
// ---------------------------------------------------------------------------
__global__ __launch_bounds__(256) void window_combine_kernel(const float* __restrict__ xw,
                                                             const float* __restrict__ T,
                                                             float* __restrict__ out) {
  const int idx = blockIdx.x * 256 + threadIdx.x;
  if (idx >= BB * NN * 16) return;
  const int b = idx / (NN * 16);
  const int rem = idx - b * (NN * 16);
  float acc = 0.f;
#pragma unroll
  for (int t = 0; t < LAGN; ++t)
    acc = fmaf(T[t], xw[(size_t)(b * LAGN + t) * (NN * 16) + rem], acc);
  out[idx] = acc;
}

// ---------------------------------------------------------------------------
// K11: MFMA fusion. One wave per node: gconv (6 MFMAs) + wconv (2 MFMAs),
// LN via 16-lane butterflies on the C-layout, concat + bias.
// ---------------------------------------------------------------------------
__global__ __launch_bounds__(256) void fuse_mfma_kernel(const float* __restrict__ x,
                                                        const float* __restrict__ Y1f,
                                                        const float* __restrict__ Y2f,
                                                        const ushort* __restrict__ Wt,
                                                        const ushort* __restrict__ wwt,
                                                        const float* __restrict__ biasN,
                                                        const float* __restrict__ xwc,
                                                        const float* __restrict__ ln1w,
                                                        const float* __restrict__ ln1b,
                                                        const float* __restrict__ ln2w,
                                                        const float* __restrict__ ln2b,
                                                        float* __restrict__ out) {
  const int tid = threadIdx.x;
  const int n = blockIdx.x * 4 + (tid >> 6);  // grid 1250*4 = 5000 exact
  const int l = tid & 63, fm = l & 15, kq = l >> 4;
  const short8 ax = cvt8(x + ((size_t)fm * NN + n) * DINC + kq * 8);
  const short8 a1 = cvt8(Y1f + (size_t)n * BC + fm * 32 + kq * 8);
  const short8 a2 = cvt8(Y2f + (size_t)n * BC + fm * 32 + kq * 8);
  short8 aw = {};
  if (kq < 2) aw = cvt8(xwc + ((size_t)fm * NN + n) * 16 + kq * 8);
  const ushort* wn = Wt + (size_t)n * 3072;
  const ushort* wwn = wwt + (size_t)n * 512;
  float4v accG[2] = {}, accW[2] = {};
#pragma unroll
  for (int t = 0; t < 2; ++t) {
    const int ob = (t * 16 + fm) * 96 + kq * 8;
    const short8 b0 = *(const short8*)(wn + ob);
    const short8 b1 = *(const short8*)(wn + ob + 32);
    const short8 b2 = *(const short8*)(wn + ob + 64);
    accG[t] = __builtin_amdgcn_mfma_f32_16x16x32_bf16(ax, b0, accG[t], 0, 0, 0);
    accG[t] = __builtin_amdgcn_mfma_f32_16x16x32_bf16(a1, b1, accG[t], 0, 0, 0);
    accG[t] = __builtin_amdgcn_mfma_f32_16x16x32_bf16(a2, b2, accG[t], 0, 0, 0);
    short8 bw = {};
    if (kq < 2) bw = *(const short8*)(wwn + (t * 16 + fm) * 16 + kq * 8);
    accW[t] = __builtin_amdgcn_mfma_f32_16x16x32_bf16(aw, bw, accW[t], 0, 0, 0);
  }
  const float w1a = ln1w[fm], w1b = ln1w[16 + fm];
  const float c1a = ln1b[fm], c1b = ln1b[16 + fm];
  const float w2a = ln2w[fm], w2b = ln2w[16 + fm];
  const float c2a = ln2b[fm], c2b = ln2b[16 + fm];
  const float* bn = biasN + (size_t)n * 64;
  const float bga = bn[fm], bgb = bn[16 + fm];
  const float bwa = bn[32 + fm], bwb = bn[48 + fm];
#pragma unroll
  for (int r = 0; r < 4; ++r) {
    const int b = kq * 4 + r;
    const float g0 = accG[0][r], g1 = accG[1][r];
    float s1 = g0 + g1, s2 = g0 * g0 + g1 * g1;
#pragma unroll
    for (int m = 1; m < 16; m <<= 1) { s1 += __shfl_xor(s1, m); s2 += __shfl_xor(s2, m); }
    const float mu = s1 * 0.03125f;
    const float rs = rsqrtf(s2 * 0.03125f - mu * mu + 1e-5f);
    const float h0 = accW[0][r], h1 = accW[1][r];
    float t1 = h0 + h1, t2 = h0 * h0 + h1 * h1;
#pragma unroll
    for (int m = 1; m < 16; m <<= 1) { t1 += __shfl_xor(t1, m); t2 += __shfl_xor(t2, m); }
    const float mu2 = t1 * 0.03125f;
    const float rs2 = rsqrtf(t2 * 0.03125f - mu2 * mu2 + 1e-5f);
    float* op = out + ((size_t)b * NN + n) * 64;
    op[fm]      = (g0 - mu) * rs * w1a + c1a + bga;
    op[16 + fm] = (g1 - mu) * rs * w1b + c1b + bgb;
    op[32 + fm] = (h0 - mu2) * rs2 * w2a + c2a + bwa;
    op[48 + fm] = (h1 - mu2) * rs2 * w2b + c2b + bwb;
  }
}

// ---------------------------------------------------------------------------
// Workspace map (fp32 slots), high-water 30,410,816 floats = 121.6 MB:
//   [0, 25M)              P bf16 rows (fused_A_softmax output; row m =
//                         ushorts [m*10000+(m&1)*16, +5120) P~,
//                         [m*10000+5160, +4096) 8 bf16 split-K partial slabs,
//                         chunk sums fp32[8] at ushort offset m*10000+9472)
//                         -> after reduce2: overlaid by Wt/wwt/biasN/xwc
//   [25.0M, 26.31072M)    XbT bf16 [512][5120]   (dead after GEMM1)
//   [26.31072M,27.62144M) Y1t bf16 [512][5120]   (dead after GEMM2)
//   [25.0M, 27.56M)       Y2f fp32 (reduce2 output, overlays XbT+Y1t)
//   [27.62144M,30.18144M) Y1f fp32; BEFORE reduce1 this region also hosts:
//       [27621440,27785280)  embH bf16 [5120][64]  (DEAD after reduce1! —
//       [27785280,27949120)  embL bf16 [5120][64]   only fused_A may read)
//       [27949120,27951680)  ascr — 5120-ushort tail-row store scratch
//   [30181440,30296128)   wtH bf16 [3584][64] (transposed hi pools; live
//   [30296128,30410816)   wtL bf16 [3584][64]  from prep to emb_wt_mfma)
// ---------------------------------------------------------------------------
extern "C" void kernel_launch(void* const* d_in, const int* in_sizes, int n_in,
                              void* d_out, int out_size, void* d_ws, size_t ws_size,
                              hipStream_t stream) {
  const float* x     = (const float*)d_in[0];
  const float* xwin  = (const float*)d_in[1];
  const float* emb   = (const float*)d_in[2];
  const float* wpool = (const float*)d_in[3];
  const float* wwin  = (const float*)d_in[4];
  const float* bpool = (const float*)d_in[5];
  const float* T     = (const float*)d_in[6];
  const float* ln1w  = (const float*)d_in[7];
  const float* ln1b  = (const float*)d_in[8];
  const float* ln2w  = (const float*)d_in[9];
  const float* ln2b  = (const float*)d_in[10];
  float* out = (float*)d_out;
  float* ws = (float*)d_ws;

  ushort* P    = (ushort*)ws;
  ushort* XbT  = (ushort*)(ws + 25000000);
  ushort* Y1t  = (ushort*)(ws + 26310720);
  float*  Y1f  = ws + 27621440;
  float*  Y2f  = ws + 25000000;        // overlays XbT+Y1t after GEMM2
  ushort* embH = (ushort*)(ws + 27621440);   // overlays Y1f until reduce1
  ushort* embL = (ushort*)(ws + 27785280);
  ushort* ascr = (ushort*)(ws + 27949120);   // 5120-ushort tail scratch
  ushort* Wt    = (ushort*)ws;         // [5000][3072] bf16, overlays P after reduce2
  ushort* wwt   = (ushort*)(ws + 15360000);  // [5000][512] bf16
  float*  biasN = ws + 17920000;
  float*  xwc   = ws + 18240000;       // overlays P rows — write after reduce2!
  ushort* wtH   = (ushort*)(ws + 30181440);  // [3584][64] bf16 hi
  ushort* wtL   = (ushort*)(ws + 30296128);  // [3584][64] bf16 lo

  prep_kernel<<<12416, 256, 0, stream>>>(x, wpool, wwin, emb, XbT, wtH, wtL, embH, embL);
  fused_A_softmax_kernel<<<1256, 256, 0, stream>>>(embH, embL, P, ascr);
  mfma_gemm_kernel<<<2560, 256, 0, stream>>>(P, XbT, P);
  reduce_kernel<<<dim3(8, 80), 256, 0, stream>>>(P, Y1f, Y1t, 1);
  mfma_gemm_kernel<<<2560, 256, 0, stream>>>(P, Y1t, P);
  reduce_kernel<<<dim3(8, 80), 256, 0, stream>>>(P, Y2f, (ushort*)nullptr, 0);
  emb_wt_mfma_kernel<<<2198, 256, 0, stream>>>(emb, wtH, wtL, Wt, wwt);
  emb_gemm_kernel<<<dim3(1, 157), 256, 0, stream>>>(emb, bpool, biasN, NN, 64);
  window_combine_kernel<<<(BB * NN * 16 + 255) / 256, 256, 0, stream>>>(xwin, T, xwc);
  fuse_mfma_kernel<<<1250, 256, 0, stream>>>(x, Y1f, Y2f, Wt, wwt, biasN, xwc,
                                             ln1w, ln1b, ln2w, ln2b, out);
}

// Round 17
// 331.454 us; speedup vs baseline: 1.0027x; 1.0027x over previous
//
#include <hip/hip_runtime.h>
#include <hip/hip_bf16.h>

// Problem constants (reference setup_inputs)
#define NN   5000   // nodes
#define EDIM 64     // embedding dim
#define DINC 32     // DIN
#define BB   16     // batch
#define LAGN 12     // LAG
#define BC   512    // BB*DINC
#define KPAD 5120   // k-extent padded to 128-tile multiple (zeros in [5000,5120))

typedef __attribute__((ext_vector_type(8))) short short8;   // 8 bf16 = 4 VGPRs
typedef __attribute__((ext_vector_type(4))) float float4v;  // MFMA 16x16 C/D

static __device__ __forceinline__ ushort f2bf(float x) {
  __hip_bfloat16 h = __float2bfloat16(x);
  return *reinterpret_cast<ushort*>(&h);
}
static __device__ __forceinline__ float bf2f(ushort u) {
  unsigned int x = ((unsigned int)u) << 16;
  return __uint_as_float(x);
}
static __device__ __forceinline__ short8 cvt8(const float* p) {  // 8 floats -> bf16x8
  const float4 v0 = *(const float4*)p, v1 = *(const float4*)(p + 4);
  short8 r;
  r[0] = (short)f2bf(v0.x); r[1] = (short)f2bf(v0.y);
  r[2] = (short)f2bf(v0.z); r[3] = (short)f2bf(v0.w);
  r[4] = (short)f2bf(v1.x); r[5] = (short)f2bf(v1.y);
  r[6] = (short)f2bf(v1.z); r[7] = (short)f2bf(v1.w);
  return r;
}

// async global->LDS DMA, 16 B per lane; LDS dst is wave-uniform base + lane*16.
static __device__ __forceinline__ void gll16(const ushort* g, ushort* l) {
  __builtin_amdgcn_global_load_lds(
      (const __attribute__((address_space(1))) void*)g,
      (__attribute__((address_space(3))) void*)l, 16, 0, 0);
}

// P row m (bf16) lives at ushort offset m*10000 + (m&1)*16  -> 64B-aligned rows.
// Split-K partial slab z for row m: ushort offset m*10000 + 5160 + z*512.
// Softmax chunk partial sums fp32[8] for row m: ushort offset m*10000 + 9472
// (16B-aligned, 32 B; spare region [9256,10000) of each row; GEMM epilogue
// tops out at 9255). reduce_kernel sums the 8 and multiplies by reciprocal.

// ---------------------------------------------------------------------------
// K0: merged prep — transpose_xb | wt hi/lo transposed pools | emb hi/lo bf16.
// R20: wpool/wwin emitted TRANSPOSED + hi/lo bf16 (wtH/wtL[col'][64]) so the
// Wt/wwt GEMM runs on MFMA with the fused_A B-fragment read pattern.
// (xwc NOT here: its buffer overlays the A/P region — write after reduce2.)
// ---------------------------------------------------------------------------
__global__ __launch_bounds__(256) void prep_kernel(const float* __restrict__ x,
                                                   const float* __restrict__ wpool,
                                                   const float* __restrict__ wwin,
                                                   const float* __restrict__ emb,
                                                   ushort* __restrict__ XbT,
                                                   ushort* __restrict__ wtH,
                                                   ushort* __restrict__ wtL,
                                                   ushort* __restrict__ eH,
                                                   ushort* __restrict__ eL) {
  const int b = blockIdx.x, tid = threadIdx.x;
  if (b < 10240) {            // XbT[j][m] = bf16(x[j>>5][m][j&31]), zero pad m>=NN
    const int j = b / 20, m = (b - j * 20) * 256 + tid;
    const int bb = j >> 5, c = j & 31;
    ushort v = 0;
    if (m < NN) v = f2bf(x[((size_t)bb * NN + m) * DINC + c]);
    XbT[(size_t)j * KPAD + m] = v;
  } else if (b < 11008) {     // wpool -> wtH/wtL[col'][d], col' = o*96+kk*32+i
    const int t = (b - 10240) * 256 + tid;    // 768*256 = 3072*64
    const int col = t >> 6, d = t & 63;
    const int o = col / 96, r2 = col - o * 96, kk = r2 >> 5, i = r2 & 31;
    const float v = wpool[(size_t)d * 3072 + kk * 1024 + i * 32 + o];
    const ushort h = f2bf(v);
    wtH[t] = h;                               // t == col*64 + d exactly
    wtL[t] = f2bf(v - bf2f(h));
  } else if (b < 11136) {     // wwin -> wtH/wtL[3072+col''][d], col'' = o*16+i
    const int t = (b - 11008) * 256 + tid;    // 128*256 = 512*64
    const int col = t >> 6, d = t & 63;
    const int o = col >> 4, i = col & 15;
    const float v = wwin[(size_t)d * 512 + i * 32 + o];
    const ushort h = f2bf(v);
    wtH[196608 + t] = h;                      // 196608 = 3072*64
    wtL[196608 + t] = f2bf(v - bf2f(h));
  } else {                    // emb -> bf16 hi + bf16 residual, rows padded to 5120
    const int t = (b - 11136) * 256 + tid;    // 1280*256 = 5120*64
    const int row = t >> 6;
    float v = 0.f;
    if (row < NN) v = emb[t];                 // t == row*64 + col exactly
    const ushort h = f2bf(v);
    eH[t] = h;
    eL[t] = f2bf(v - bf2f(h));
  }
}

// ---------------------------------------------------------------------------
// K1: fused A + exp, MFMA, no fp32 A intermediate, DIAG-SHIFT (R12).
// Normalization is deferred to the reduce kernels; any per-row constant c_m
// cancels exactly in e/sum — c_m = diag |e_m|^2 bounds the exponent. Each
// chunk-block recomputes the IDENTICAL diag from identical fragments
// (deterministic FP) -> all chunk sums of a row share one shift.
// R18: LDS-STAGED B-SIDE with global_load_lds + LDS dbuf. R23 (verified,
// -8 us): 8-way column split (grid 1256, 5 tiles/block) fixes the 2-round
// quantization at 2 blocks/CU. Chunk sums -> fp32[8] at 9472+2*ch.
// Per tile: stage(t+1) || MFMA+exp -> barrier -> stores (R22 ordering).
// Grid 1256 = 157 row-groups x 8 chunks of 640 cols; 5 tiles of 128 cols.
// ---------------------------------------------------------------------------
__global__ __launch_bounds__(256) void fused_A_softmax_kernel(const ushort* __restrict__ eH,
                                                              const ushort* __restrict__ eL,
                                                              ushort* __restrict__ P,
                                                              ushort* __restrict__ scr) {
  __shared__ __align__(16) ushort Ls[32768];  // 64 KB: [2 bufs][H 8192 | L 8192]
  const int tid = threadIdx.x;
  const int w = tid >> 6, l = tid & 63;
  const int fm = l & 15, kq = l >> 4;
  const int rg = blockIdx.x >> 3, ch = blockIdx.x & 7;  // grid 1256
  const int row0 = rg * 32;                   // rows 0..5023
  const int cbase = ch * 640;
  __shared__ float redL[4][32];
  __shared__ float diagL[32];

  // staging decode (mfma_gemm pattern): call q covers tile-rows q*32+(tid>>3),
  // chunk slot tid&7 (XOR-swizzled); LDS dst = wave-uniform + lane*16.
  const int rstg = tid >> 3;            // 0..31
  const int slot = tid & 7;
  ushort* lH = Ls + tid * 8;            // + buf*16384 + q*2048
  ushort* lL = Ls + 8192 + tid * 8;

  auto stage = [&](int buf, int t) {
    const int c0 = cbase + t * 128;
#pragma unroll
    for (int q = 0; q < 4; ++q) {
      const int r = q * 32 + rstg;
      const int cg = slot ^ (r & 7);
      gll16(eH + (size_t)(c0 + r) * 64 + cg * 8, lH + buf * 16384 + q * 2048);
    }
#pragma unroll
    for (int q = 0; q < 4; ++q) {
      const int r = q * 32 + rstg;
      const int cg = slot ^ (r & 7);
      gll16(eL + (size_t)(c0 + r) * 64 + cg * 8, lL + buf * 16384 + q * 2048);
    }
  };

  // A-side fragments (32 rows), loaded once: frag row = fm, k-slot = s*4+kq
  short8 aH[2][2], aL[2][2];
#pragma unroll
  for (int mf = 0; mf < 2; ++mf)
#pragma unroll
    for (int s = 0; s < 2; ++s) {
      const size_t o = (size_t)(row0 + mf * 16 + fm) * 64 + (s * 4 + kq) * 8;
      aH[mf][s] = *(const short8*)(eH + o);
      aL[mf][s] = *(const short8*)(eL + o);
    }

  stage(0, 0);   // tile-0 DMAs in flight under the diag reduction below

  // Per-row diag |e_row|^2 from the fragments: lane covers 16 of 64 elems
  // (k-slots kq and 4+kq); butterfly over the kq lane bits (16, 32).
#pragma unroll
  for (int mf = 0; mf < 2; ++mf) {
    float p = 0.f;
#pragma unroll
    for (int s = 0; s < 2; ++s)
#pragma unroll
      for (int j = 0; j < 8; ++j) {
        const float v = bf2f((ushort)aH[mf][s][j]) + bf2f((ushort)aL[mf][s][j]);
        p = fmaf(v, v, p);
      }
    p += __shfl_xor(p, 16);
    p += __shfl_xor(p, 32);
    if (w == 0 && kq == 0) diagL[mf * 16 + fm] = p;   // row mf*16+fm
  }
  __syncthreads();   // diagL visible AND tile-0 DMAs drained (vmcnt(0))
  float shift[2][4];
#pragma unroll
  for (int mf = 0; mf < 2; ++mf)
#pragma unroll
    for (int r = 0; r < 4; ++r) shift[mf][r] = diagL[mf * 16 + kq * 4 + r];

  float rs[2][4] = {};
  ushort* prow[2][4];
#pragma unroll
  for (int mf = 0; mf < 2; ++mf)
#pragma unroll
    for (int r = 0; r < 4; ++r) {
      const int gm = row0 + mf * 16 + kq * 4 + r;
      prow[mf][r] = (gm < NN) ? (P + (size_t)gm * 10000 + (gm & 1) * 16) : scr;
    }

  int cur = 0;
  for (int t = 0; t < 5; ++t) {
    if (t < 4) stage(cur ^ 1, t + 1);   // issue tile t+1 DMAs (overlap below)
    const ushort* H = Ls + cur * 16384;
    const ushort* L = H + 8192;
    const int c0 = cbase + t * 128;
    float4v acc[2][2] = {};
#pragma unroll
    for (int s = 0; s < 2; ++s) {
      short8 bh[2], bl[2];
#pragma unroll
      for (int nf = 0; nf < 2; ++nf) {
        const int row = w * 32 + nf * 16 + fm;      // local col within tile
        const int sl = (s * 4 + kq) ^ (fm & 7);
        bh[nf] = *(const short8*)(H + row * 64 + sl * 8);
        bl[nf] = *(const short8*)(L + row * 64 + sl * 8);
      }
#pragma unroll
      for (int mf = 0; mf < 2; ++mf)
#pragma unroll
        for (int nf = 0; nf < 2; ++nf) {
          acc[mf][nf] = __builtin_amdgcn_mfma_f32_16x16x32_bf16(aL[mf][s], bh[nf], acc[mf][nf], 0, 0, 0);
          acc[mf][nf] = __builtin_amdgcn_mfma_f32_16x16x32_bf16(aH[mf][s], bl[nf], acc[mf][nf], 0, 0, 0);
          acc[mf][nf] = __builtin_amdgcn_mfma_f32_16x16x32_bf16(aH[mf][s], bh[nf], acc[mf][nf], 0, 0, 0);
        }
    }
    // exp/VALU epilogue BEFORE the barrier (covers the in-flight DMAs);
    // values parked in statically-indexed regs.
    ushort ev[2][2][4];
#pragma unroll
    for (int nf = 0; nf < 2; ++nf) {
      const int col = c0 + w * 32 + nf * 16 + fm;
      const bool ok = col < NN;               // k-pad cols [5000,5120) -> exact 0
#pragma unroll
      for (int mf = 0; mf < 2; ++mf)
#pragma unroll
        for (int r = 0; r < 4; ++r) {
          const float v = fmaxf(acc[mf][nf][r], 0.f);   // relu
          const float e = ok ? __expf(v - shift[mf][r]) : 0.f;
          rs[mf][r] += e;
          ev[nf][mf][r] = f2bf(e);
        }
    }
    __builtin_amdgcn_sched_barrier(0);  // pin the exp VALU before the barrier
    if (t < 4) __syncthreads();         // drains aged DMAs + PREV tile's stores
    // stores AFTER the barrier: their drain is deferred to the next barrier.
#pragma unroll
    for (int nf = 0; nf < 2; ++nf) {
      const int col = c0 + w * 32 + nf * 16 + fm;
#pragma unroll
      for (int mf = 0; mf < 2; ++mf)
#pragma unroll
        for (int r = 0; r < 4; ++r)
          prow[mf][r][col] = ev[nf][mf][r];
    }
    cur ^= 1;
  }

  // chunk sums: shfl over the 16 fm-lanes, LDS over the 4 waves, write fp32
  // at row spare offset 9472 + 2*ch (ch = 0..7).
#pragma unroll
  for (int mf = 0; mf < 2; ++mf)
#pragma unroll
    for (int r = 0; r < 4; ++r) {
      float v = rs[mf][r];
#pragma unroll
      for (int msk = 1; msk < 16; msk <<= 1) v += __shfl_xor(v, msk);
      rs[mf][r] = v;
    }
  __syncthreads();           // redL region reuse barrier (after compute loop)
  if (fm == 0) {
#pragma unroll
    for (int mf = 0; mf < 2; ++mf)
#pragma unroll
      for (int r = 0; r < 4; ++r) redL[w][mf * 16 + kq * 4 + r] = rs[mf][r];
  }
  __syncthreads();
  if (w == 0 && fm == 0) {
#pragma unroll
    for (int mf = 0; mf < 2; ++mf)
#pragma unroll
      for (int r = 0; r < 4; ++r) {
        const int mm = mf * 16 + kq * 4 + r;
        const int gm = row0 + mm;
        if (gm < NN) {
          const float tot = redL[0][mm] + redL[1][mm] + redL[2][mm] + redL[3][mm];
          *(float*)(P + (size_t)gm * 10000 + 9472 + 2 * ch) = tot;
        }
      }
  }
}

// ---------------------------------------------------------------------------
// K3/K5: bf16 MFMA GEMM. BM=BN=128, BK=64, 256 thr = 4 waves (2x2 of 64x64,
// 32 MFMAs/wave/iter). Split-K=8 (k-chunk 640 = 10 iters), 1D grid 1280.
// R16 REVERT to the R14-verified config: R15's BN=64 experiment REGRESSED
// (42.8 -> 49 us): halving BN halved MFMAs/iter (32->16) at constant
// per-iter overhead (2 barriers + DMA issue) — overhead fraction per MFMA
// doubled, and A-side L2 traffic doubled (8 xb sharers vs 4). Occupancy DID
// rise 15->25% as predicted but couldn't compensate. BM=BN=128 + yb-outer
// decode is the measured optimum of this 2-phase structure (626 TF = the
// template ceiling); going past it needs the 8-phase/counted-vmcnt rewrite.
// R19 (verified): YB-OUTER XCD-AWARE DECODE — yb = id>>5, xb = (id>>3)&3,
// zb = id&7 keeps XCD = zb but runs yb-major with xb inner: co-resident set
// per XCD = 16 yb x 4 xb -> A 2.6 MB + B-slice 0.65 MB < 4 MB L2; A-tiles
// fetched from L3 once (xb sharers adjacent), B-tiles L2-hot.
// R13: 2-phase dbuf pipeline (stage k+1 before compute k; one barrier/iter —
// its vmcnt(0) drain is the "tile landed" wait, after the MFMAs). LDS 64 KB.
// R9 DMA locality: each wave-instr loads 8 ROWS x 128 B. Bank conflicts
// avoided by GLOBAL-side k-chunk XOR swizzle (lane fetches chunk
// slot^(row&7); frag reads slot (s*4+kq)^(fm&7)) — measured 0 conflicts.
// ---------------------------------------------------------------------------
__global__ __launch_bounds__(256) void mfma_gemm_kernel(const ushort* __restrict__ Pm,
                                                        const ushort* __restrict__ Bt,
                                                        ushort* __restrict__ Pp) {
  __shared__ __align__(16) ushort Ls[32768];  // [2 bufs][As 8192 | Bs 8192]
  const int tid = threadIdx.x;
  const int w = tid >> 6, l = tid & 63;
  const int fm = l & 15, kq = l >> 4;
  const int wm = w >> 1, wn = w & 1;
  const int id = blockIdx.x;            // 0..1279
  const int yb = id >> 5;               // row tile 0..39  (OUTER)
  const int xb = (id >> 3) & 3;         // col tile 0..3   (inner)
  const int zb = id & 7;                // k-chunk 0..7 (= XCD)
  const int row0 = yb * 128, col0 = xb * 128;
  const int kbase = zb * 640;
  // staging: call q covers rows q*32+(tid>>3), chunk slot tid&7 (XOR-swizzled)
  const int rstg = tid >> 3;            // 0..31
  const int slot = tid & 7;
  const ushort* gAq[4];
  const ushort* gBq[4];
#pragma unroll
  for (int q = 0; q < 4; ++q) {
    const int r = q * 32 + rstg;
    const int cg = slot ^ (r & 7);      // global k-chunk this lane fetches
    const int arow = row0 + r;
    gAq[q] = Pm + (size_t)arow * 10000 + (arow & 1) * 16 + kbase + cg * 8;
    gBq[q] = Bt + (size_t)(col0 + r) * KPAD + kbase + cg * 8;
  }
  ushort* lA = Ls + tid * 8;            // + buf*16384 + q*2048 (row-major exact)
  ushort* lB = Ls + 8192 + tid * 8;
  float4v acc[4][4] = {};

  auto stage = [&](int buf) {
#pragma unroll
    for (int q = 0; q < 4; ++q) gll16(gAq[q], lA + buf * 16384 + q * 2048);
#pragma unroll
    for (int q = 0; q < 4; ++q) gll16(gBq[q], lB + buf * 16384 + q * 2048);
#pragma unroll
    for (int q = 0; q < 4; ++q) { gAq[q] += 64; gBq[q] += 64; }
  };
  auto compute = [&](int buf) {
    const ushort* As = Ls + buf * 16384;
    const ushort* Bs = As + 8192;
#pragma unroll
    for (int s = 0; s < 2; ++s) {
      short8 a[4], b[4];
#pragma unroll
      for (int mt = 0; mt < 4; ++mt) {
        const int row = wm * 64 + mt * 16 + fm;
        const int sl = (s * 4 + kq) ^ (fm & 7);
        a[mt] = *(const short8*)(As + row * 64 + sl * 8);
      }
#pragma unroll
      for (int nt = 0; nt < 4; ++nt) {
        const int row = wn * 64 + nt * 16 + fm;
        const int sl = (s * 4 + kq) ^ (fm & 7);
        b[nt] = *(const short8*)(Bs + row * 64 + sl * 8);
      }
#pragma unroll
      for (int mt = 0; mt < 4; ++mt)
#pragma unroll
        for (int nt = 0; nt < 4; ++nt)
          acc[mt][nt] = __builtin_amdgcn_mfma_f32_16x16x32_bf16(a[mt], b[nt], acc[mt][nt], 0, 0, 0);
    }
  };

  stage(0);          // prologue: tile 0 -> buf 0
  __syncthreads();   // vmcnt(0) drain + barrier: buf0 ready
  int cur = 0;
  for (int kt = 0; kt < 9; ++kt) {
    stage(cur ^ 1);  // issue tile kt+1 DMAs (async, overlap with MFMAs below)
    compute(cur);
    __syncthreads(); // drains this iter's DMAs (tile kt+1 ready) + all waves
    cur ^= 1;        // done reading buf cur -> safe to overwrite next iter
  }
  compute(cur);      // last tile, no prefetch

  // epilogue: bf16 partials into the P rows' free halves
  const int cb = col0 + wn * 64 + fm;
  const int zoff = 5160 + zb * 512;
#pragma unroll
  for (int mt = 0; mt < 4; ++mt)
#pragma unroll
    for (int r = 0; r < 4; ++r) {
      const int gm = row0 + wm * 64 + mt * 16 + kq * 4 + r;
      if (gm < NN) {
        ushort* prow = Pp + (size_t)gm * 10000 + zoff + cb;
#pragma unroll
        for (int nt = 0; nt < 4; ++nt) prow[nt * 16] = f2bf(acc[mt][nt][r]);
      }
    }
}

// ---------------------------------------------------------------------------
// K4/K6: sum 8 bf16 split-K partials, SCALE by the row's deferred softmax
// inverse sum (1 / sum of the 8 fp32 chunk sums at P-row ushort offset 9472,
// two 16B-aligned float4s) -> Yf fp32 [5000][512]; optionally also Yt bf16
// [512][KPAD] (transposed, zero pad m in [5000,5120)). Grid (8,80).
// ---------------------------------------------------------------------------
__global__ __launch_bounds__(256) void reduce_kernel(const ushort* __restrict__ Pp,
                                                     float* __restrict__ Yf,
                                                     ushort* __restrict__ Yt,
                                                     int writeT) {
  const int m0 = blockIdx.y * 64, n0 = blockIdx.x * 64;
  __shared__ __align__(16) ushort Lt[64][80];  // [n][m]
  const int tid = threadIdx.x;
  const int mi = tid >> 4, nl4 = (tid & 15) << 2;
#pragma unroll
  for (int s = 0; s < 4; ++s) {
    const int m = m0 + mi + s * 16;
    float4 sum = make_float4(0.f, 0.f, 0.f, 0.f);
    if (m < NN) {
      const ushort* pr = Pp + (size_t)m * 10000 + 5160 + n0 + nl4;
#pragma unroll
      for (int z = 0; z < 8; ++z) {
        ushort4 u = *(const ushort4*)(pr + z * 512);
        sum.x += bf2f(u.x); sum.y += bf2f(u.y);
        sum.z += bf2f(u.z); sum.w += bf2f(u.w);
      }
      const float4 s4a = *(const float4*)(Pp + (size_t)m * 10000 + 9472);
      const float4 s4b = *(const float4*)(Pp + (size_t)m * 10000 + 9480);
      const float sc = 1.f / (s4a.x + s4a.y + s4a.z + s4a.w +
                              s4b.x + s4b.y + s4b.z + s4b.w);
      sum.x *= sc; sum.y *= sc; sum.z *= sc; sum.w *= sc;
      *(float4*)(Yf + (size_t)m * BC + n0 + nl4) = sum;
    }
    if (writeT) {
      const int ml = mi + s * 16;
      Lt[nl4 + 0][ml] = f2bf(sum.x);
      Lt[nl4 + 1][ml] = f2bf(sum.y);
      Lt[nl4 + 2][ml] = f2bf(sum.z);
      Lt[nl4 + 3][ml] = f2bf(sum.w);
    }
  }
  if (writeT) {
    __syncthreads();
#pragma unroll
    for (int i = 0; i < 2; ++i) {
      const int g = tid + i * 256;
      const int nl = g >> 3, gi = g & 7;
      *(uint4*)(Yt + (size_t)(n0 + nl) * KPAD + m0 + gi * 8) =
          *(const uint4*)(&Lt[nl][gi * 8]);
    }
  }
}

// ---------------------------------------------------------------------------
// K7: Wt/wwt via MFMA (R20/R21). A-frags built from the fp32 emb INPUT on
// the fly (hi/lo split, deterministic) — NOT from embH/embL, which overlay
// Y1f and are DEAD after reduce1. C[gm][col] = sum_d emb[gm][d]*wt[col][d],
// col in [0,3584): [0,3072) -> Wt (stride 3072), [3072,3584) -> wwt (512).
// Grid 157 x 14 col-chunks of 256 = 2198 blocks. B-frags direct from
// L2-resident wtH/wtL (448 KB each, untouched between prep and here).
// 48 MFMAs/block, 3-term hi/lo. Pad rows zero-guarded / store-guarded.
// ---------------------------------------------------------------------------
__global__ __launch_bounds__(256) void emb_wt_mfma_kernel(const float* __restrict__ emb,
                                                          const ushort* __restrict__ wtH,
                                                          const ushort* __restrict__ wtL,
                                                          ushort* __restrict__ Wt,
                                                          ushort* __restrict__ wwt) {
  const int tid = threadIdx.x;
  const int w = tid >> 6, l = tid & 63;
  const int fm = l & 15, kq = l >> 4;
  const int rg = blockIdx.x / 14, cc = blockIdx.x % 14;  // 157 x 14
  const int row0 = rg * 32;                   // rows 0..5023
  const int c0 = cc * 256 + w * 64;           // wave's col base in [0,3584)

  short8 aH[2][2], aL[2][2];
#pragma unroll
  for (int mf = 0; mf < 2; ++mf) {
    const int gr = row0 + mf * 16 + fm;
#pragma unroll
    for (int s = 0; s < 2; ++s) {
      short8 h = {}, lo = {};
      if (gr < NN) {
        const float* p = emb + (size_t)gr * EDIM + (s * 4 + kq) * 8;
        const float4 v0 = *(const float4*)p, v1 = *(const float4*)(p + 4);
        const float vv[8] = {v0.x, v0.y, v0.z, v0.w, v1.x, v1.y, v1.z, v1.w};
#pragma unroll
        for (int j = 0; j < 8; ++j) {
          const ushort hh = f2bf(vv[j]);
          h[j] = (short)hh;
          lo[j] = (short)f2bf(vv[j] - bf2f(hh));
        }
      }
      aH[mf][s] = h;
      aL[mf][s] = lo;
    }
  }

  float4v acc[2][4] = {};
#pragma unroll
  for (int s = 0; s < 2; ++s) {
    short8 bh[4], bl[4];
#pragma unroll
    for (int nf = 0; nf < 4; ++nf) {
      const size_t o = (size_t)(c0 + nf * 16 + fm) * 64 + (s * 4 + kq) * 8;
      bh[nf] = *(const short8*)(wtH + o);
      bl[nf] = *(const short8*)(wtL + o);
    }
#pragma unroll
    for (int mf = 0; mf < 2; ++mf)
#pragma unroll
      for (int nf = 0; nf < 4; ++nf) {
        acc[mf][nf] = __builtin_amdgcn_mfma_f32_16x16x32_bf16(aL[mf][s], bh[nf], acc[mf][nf], 0, 0, 0);
        acc[mf][nf] = __builtin_amdgcn_mfma_f32_16x16x32_bf16(aH[mf][s], bl[nf], acc[mf][nf], 0, 0, 0);
        acc[mf][nf] = __builtin_amdgcn_mfma_f32_16x16x32_bf16(aH[mf][s], bh[nf], acc[mf][nf], 0, 0, 0);
      }
  }
#pragma unroll
  for (int nf = 0; nf < 4; ++nf) {
    const int col = c0 + nf * 16 + fm;
#pragma unroll
    for (int mf = 0; mf < 2; ++mf)
#pragma unroll
      for (int r = 0; r < 4; ++r) {
        const int gm = row0 + mf * 16 + kq * 4 + r;
        if (gm < NN) {
          const ushort v = f2bf(acc[mf][nf][r]);
          if (col < 3072) Wt[(size_t)gm * 3072 + col] = v;
          else            wwt[(size_t)gm * 512 + (col - 3072)] = v;
        }
      }
  }
}

// ---------------------------------------------------------------------------
// K9: biasN fp32 [5000][64] = emb @ bias_pool.
// ---------------------------------------------------------------------------
__global__ __launch_bounds__(256) void emb_gemm_kernel(const float* __restrict__ Ae,
                                                       const float* __restrict__ Bw,
                                                       float* __restrict__ C,
                                                       int M, int Nc) {
  __shared__ float Aet[EDIM][33];
  __shared__ __align__(16) float Bs[EDIM][64];
  const int row0 = blockIdx.y * 32, col0 = blockIdx.x * 64;
  const int tid = threadIdx.x;
  for (int i = tid; i < 512; i += 256) {
    const int r = i >> 4, d4 = (i & 15) << 2;
    const int gm = row0 + r;
    float4 v = make_float4(0.f, 0.f, 0.f, 0.f);
    if (gm < M) v = *(const float4*)(Ae + (size_t)gm * EDIM + d4);
    Aet[d4 + 0][r] = v.x; Aet[d4 + 1][r] = v.y; Aet[d4 + 2][r] = v.z; Aet[d4 + 3][r] = v.w;
  }
  for (int i = tid; i < 1024; i += 256) {
    const int br = i >> 4, bc = (i & 15) << 2;
    if (bc < Nc) *(float4*)&Bs[br][bc] = *(const float4*)(Bw + (size_t)br * Nc + bc);
  }
  __syncthreads();
  const int ty = tid >> 4, tx = tid & 15;
  float acc[2][4] = {};
#pragma unroll 8
  for (int d = 0; d < EDIM; ++d) {
    const float a0 = Aet[d][ty * 2], a1 = Aet[d][ty * 2 + 1];
    const float4 b4 = *(const float4*)&Bs[d][tx << 2];
    acc[0][0] = fmaf(a0, b4.x, acc[0][0]); acc[0][1] = fmaf(a0, b4.y, acc[0][1]);
    acc[0][2] = fmaf(a0, b4.z, acc[0][2]); acc[0][3] = fmaf(a0, b4.w, acc[0][3]);
    acc[1][0] = fmaf(a1, b4.x, acc[1][0]); acc[1][1] = fmaf(a1, b4.y, acc[1][1]);
    acc[1][2] = fmaf(a1, b4.z, acc[1][2]); acc[1][3] = fmaf(a1, b4.w, acc[1][3]);
  }
#pragma unroll
  for (int r = 0; r < 2; ++r) {
    const int gm = row0 + ty * 2 + r;
    if (gm >= M) continue;
    float4 o;
    o.x = acc[r][0]; o.y = acc[r][1]; o.z = acc[r][2]; o.w = acc[r][3];
    *(float4*)(C + (size_t)gm * Nc + col0 + (tx << 2)) = o;
  }
}

// ---------------------------------------------------------------------------
// K10: xwc[b, n, i] = sum_t T[t] * x_window[b, t, n, i]
// (launched AFTER reduce2: xwc buffer overlays the dead A/P region)
// ---------------------------------------------------------------------------
__global__ __launch_bounds__(256) void window_combine_kernel(const float* __restrict__ xw,
                                                             const float* __restrict__ T,
                                                             float* __restrict__ out) {
  const int idx = blockIdx.x * 256 + threadIdx.x;
  if (idx >= BB * NN * 16) return;
  const int b = idx / (NN * 16);
  const int rem = idx - b * (NN * 16);
  float acc = 0.f;
#pragma unroll
  for (int t = 0; t < LAGN; ++t)
    acc = fmaf(T[t], xw[(size_t)(b * LAGN + t) * (NN * 16) + rem], acc);
  out[idx] = acc;
}

// ---------------------------------------------------------------------------
// K11: MFMA fusion. One wave per node: gconv (6 MFMAs) + wconv (2 MFMAs),
// LN via 16-lane butterflies on the C-layout, concat + bias.
// ---------------------------------------------------------------------------
__global__ __launch_bounds__(256) void fuse_mfma_kernel(const float* __restrict__ x,
                                                        const float* __restrict__ Y1f,
                                                        const float* __restrict__ Y2f,
                                                        const ushort* __restrict__ Wt,
                                                        const ushort* __restrict__ wwt,
                                                        const float* __restrict__ biasN,
                                                        const float* __restrict__ xwc,
                                                        const float* __restrict__ ln1w,
                                                        const float* __restrict__ ln1b,
                                                        const float* __restrict__ ln2w,
                                                        const float* __restrict__ ln2b,
                                                        float* __restrict__ out) {
  const int tid = threadIdx.x;
  const int n = blockIdx.x * 4 + (tid >> 6);  // grid 1250*4 = 5000 exact
  const int l = tid & 63, fm = l & 15, kq = l >> 4;
  const short8 ax = cvt8(x + ((size_t)fm * NN + n) * DINC + kq * 8);
  const short8 a1 = cvt8(Y1f + (size_t)n * BC + fm * 32 + kq * 8);
  const short8 a2 = cvt8(Y2f + (size_t)n * BC + fm * 32 + kq * 8);
  short8 aw = {};
  if (kq < 2) aw = cvt8(xwc + ((size_t)fm * NN + n) * 16 + kq * 8);
  const ushort* wn = Wt + (size_t)n * 3072;
  const ushort* wwn = wwt + (size_t)n * 512;
  float4v accG[2] = {}, accW[2] = {};
#pragma unroll
  for (int t = 0; t < 2; ++t) {
    const int ob = (t * 16 + fm) * 96 + kq * 8;
    const short8 b0 = *(const short8*)(wn + ob);
    const short8 b1 = *(const short8*)(wn + ob + 32);
    const short8 b2 = *(const short8*)(wn + ob + 64);
    accG[t] = __builtin_amdgcn_mfma_f32_16x16x32_bf16(ax, b0, accG[t], 0, 0, 0);
    accG[t] = __builtin_amdgcn_mfma_f32_16x16x32_bf16(a1, b1, accG[t], 0, 0, 0);
    accG[t] = __builtin_amdgcn_mfma_f32_16x16x32_bf16(a2, b2, accG[t], 0, 0, 0);
    short8 bw = {};
    if (kq < 2) bw = *(const short8*)(wwn + (t * 16 + fm) * 16 + kq * 8);
    accW[t] = __builtin_amdgcn_mfma_f32_16x16x32_bf16(aw, bw, accW[t], 0, 0, 0);
  }
  const float w1a = ln1w[fm], w1b = ln1w[16 + fm];
  const float c1a = ln1b[fm], c1b = ln1b[16 + fm];
  const float w2a = ln2w[fm], w2b = ln2w[16 + fm];
  const float c2a = ln2b[fm], c2b = ln2b[16 + fm];
  const float* bn = biasN + (size_t)n * 64;
  const float bga = bn[fm], bgb = bn[16 + fm];
  const float bwa = bn[32 + fm], bwb = bn[48 + fm];
#pragma unroll
  for (int r = 0; r < 4; ++r) {
    const int b = kq * 4 + r;
    const float g0 = accG[0][r], g1 = accG[1][r];
    float s1 = g0 + g1, s2 = g0 * g0 + g1 * g1;
#pragma unroll
    for (int m = 1; m < 16; m <<= 1) { s1 += __shfl_xor(s1, m); s2 += __shfl_xor(s2, m); }
    const float mu = s1 * 0.03125f;
    const float rs = rsqrtf(s2 * 0.03125f - mu * mu + 1e-5f);
    const float h0 = accW[0][r], h1 = accW[1][r];
    float t1 = h0 + h1, t2 = h0 * h0 + h1 * h1;
#pragma unroll
    for (int m = 1; m < 16; m <<= 1) { t1 += __shfl_xor(t1, m); t2 += __shfl_xor(t2, m); }
    const float mu2 = t1 * 0.03125f;
    const float rs2 = rsqrtf(t2 * 0.03125f - mu2 * mu2 + 1e-5f);
    float* op = out + ((size_t)b * NN + n) * 64;
    op[fm]      = (g0 - mu) * rs * w1a + c1a + bga;
    op[16 + fm] = (g1 - mu) * rs * w1b + c1b + bgb;
    op[32 + fm] = (h0 - mu2) * rs2 * w2a + c2a + bwa;
    op[48 + fm] = (h1 - mu2) * rs2 * w2b + c2b + bwb;
  }
}

// ---------------------------------------------------------------------------
// Workspace map (fp32 slots), high-water 30,410,816 floats = 121.6 MB:
//   [0, 25M)              P bf16 rows (fused_A_softmax output; row m =
//                         ushorts [m*10000+(m&1)*16, +5120) P~,
//                         [m*10000+5160, +4096) 8 bf16 split-K partial slabs,
//                         chunk sums fp32[8] at ushort offset m*10000+9472)
//                         -> after reduce2: overlaid by Wt/wwt/biasN/xwc
//   [25.0M, 26.31072M)    XbT bf16 [512][5120]   (dead after GEMM1)
//   [26.31072M,27.62144M) Y1t bf16 [512][5120]   (dead after GEMM2)
//   [25.0M, 27.56M)       Y2f fp32 (reduce2 output, overlays XbT+Y1t)
//   [27.62144M,30.18144M) Y1f fp32; BEFORE reduce1 this region also hosts:
//       [27621440,27785280)  embH bf16 [5120][64]  (DEAD after reduce1! —
//       [27785280,27949120)  embL bf16 [5120][64]   only fused_A may read)
//       [27949120,27951680)  ascr — 5120-ushort tail-row store scratch
//   [30181440,30296128)   wtH bf16 [3584][64] (transposed hi pools; live
//   [30296128,30410816)   wtL bf16 [3584][64]  from prep to emb_wt_mfma)
// ---------------------------------------------------------------------------
extern "C" void kernel_launch(void* const* d_in, const int* in_sizes, int n_in,
                              void* d_out, int out_size, void* d_ws, size_t ws_size,
                              hipStream_t stream) {
  const float* x     = (const float*)d_in[0];
  const float* xwin  = (const float*)d_in[1];
  const float* emb   = (const float*)d_in[2];
  const float* wpool = (const float*)d_in[3];
  const float* wwin  = (const float*)d_in[4];
  const float* bpool = (const float*)d_in[5];
  const float* T     = (const float*)d_in[6];
  const float* ln1w  = (const float*)d_in[7];
  const float* ln1b  = (const float*)d_in[8];
  const float* ln2w  = (const float*)d_in[9];
  const float* ln2b  = (const float*)d_in[10];
  float* out = (float*)d_out;
  float* ws = (float*)d_ws;

  ushort* P    = (ushort*)ws;
  ushort* XbT  = (ushort*)(ws + 25000000);
  ushort* Y1t  = (ushort*)(ws + 26310720);
  float*  Y1f  = ws + 27621440;
  float*  Y2f  = ws + 25000000;        // overlays XbT+Y1t after GEMM2
  ushort* embH = (ushort*)(ws + 27621440);   // overlays Y1f until reduce1
  ushort* embL = (ushort*)(ws + 27785280);
  ushort* ascr = (ushort*)(ws + 27949120);   // 5120-ushort tail scratch
  ushort* Wt    = (ushort*)ws;         // [5000][3072] bf16, overlays P after reduce2
  ushort* wwt   = (ushort*)(ws + 15360000);  // [5000][512] bf16
  float*  biasN = ws + 17920000;
  float*  xwc   = ws + 18240000;       // overlays P rows — write after reduce2!
  ushort* wtH   = (ushort*)(ws + 30181440);  // [3584][64] bf16 hi
  ushort* wtL   = (ushort*)(ws + 30296128);  // [3584][64] bf16 lo

  prep_kernel<<<12416, 256, 0, stream>>>(x, wpool, wwin, emb, XbT, wtH, wtL, embH, embL);
  fused_A_softmax_kernel<<<1256, 256, 0, stream>>>(embH, embL, P, ascr);
  mfma_gemm_kernel<<<1280, 256, 0, stream>>>(P, XbT, P);
  reduce_kernel<<<dim3(8, 80), 256, 0, stream>>>(P, Y1f, Y1t, 1);
  mfma_gemm_kernel<<<1280, 256, 0, stream>>>(P, Y1t, P);
  reduce_kernel<<<dim3(8, 80), 256, 0, stream>>>(P, Y2f, (ushort*)nullptr, 0);
  emb_wt_mfma_kernel<<<2198, 256, 0, stream>>>(emb, wtH, wtL, Wt, wwt);
  emb_gemm_kernel<<<dim3(1, 157), 256, 0, stream>>>(emb, bpool, biasN, NN, 64);
  window_combine_kernel<<<(BB * NN * 16 + 255) / 256, 256, 0, stream>>>(xwin, T, xwc);
  fuse_mfma_kernel<<<1250, 256, 0, stream>>>(x, Y1f, Y2f, Wt, wwt, biasN, xwc,
                                             ln1w, ln1b, ln2w, ln2b, out);
}

// Round 18
// 331.144 us; speedup vs baseline: 1.0036x; 1.0009x over previous
//
#include <hip/hip_runtime.h>
#include <hip/hip_bf16.h>

// Problem constants (reference setup_inputs)
#define NN   5000   // nodes
#define EDIM 64     // embedding dim
#define DINC 32     // DIN
#define BB   16     // batch
#define LAGN 12     // LAG
#define BC   512    // BB*DINC
#define KPAD 5120   // k-extent padded to 128-tile multiple (zeros in [5000,5120))

typedef __attribute__((ext_vector_type(8))) short short8;    // 8 bf16 = 4 VGPRs
typedef __attribute__((ext_vector_type(4))) float float4v;   // MFMA 16x16 C/D
typedef __attribute__((ext_vector_type(16))) float float16v; // MFMA 32x32 C/D

static __device__ __forceinline__ ushort f2bf(float x) {
  __hip_bfloat16 h = __float2bfloat16(x);
  return *reinterpret_cast<ushort*>(&h);
}
static __device__ __forceinline__ float bf2f(ushort u) {
  unsigned int x = ((unsigned int)u) << 16;
  return __uint_as_float(x);
}
static __device__ __forceinline__ short8 cvt8(const float* p) {  // 8 floats -> bf16x8
  const float4 v0 = *(const float4*)p, v1 = *(const float4*)(p + 4);
  short8 r;
  r[0] = (short)f2bf(v0.x); r[1] = (short)f2bf(v0.y);
  r[2] = (short)f2bf(v0.z); r[3] = (short)f2bf(v0.w);
  r[4] = (short)f2bf(v1.x); r[5] = (short)f2bf(v1.y);
  r[6] = (short)f2bf(v1.z); r[7] = (short)f2bf(v1.w);
  return r;
}

// async global->LDS DMA, 16 B per lane; LDS dst is wave-uniform base + lane*16.
static __device__ __forceinline__ void gll16(const ushort* g, ushort* l) {
  __builtin_amdgcn_global_load_lds(
      (const __attribute__((address_space(1))) void*)g,
      (__attribute__((address_space(3))) void*)l, 16, 0, 0);
}

// P row m (bf16) lives at ushort offset m*10000 + (m&1)*16  -> 64B-aligned rows.
// Split-K partial slab z for row m: ushort offset m*10000 + 5160 + z*512.
// Softmax chunk partial sums fp32[8] for row m: ushort offset m*10000 + 9472
// (16B-aligned, 32 B; spare region [9256,10000) of each row; GEMM epilogue
// tops out at 9255). reduce_kernel sums the 8 and multiplies by reciprocal.

// ---------------------------------------------------------------------------
// K0: merged prep — transpose_xb | wt hi/lo transposed pools | emb hi/lo bf16.
// R20: wpool/wwin emitted TRANSPOSED + hi/lo bf16 (wtH/wtL[col'][64]) so the
// Wt/wwt GEMM runs on MFMA with the fused_A B-fragment read pattern.
// (xwc NOT here: its buffer overlays the A/P region — write after reduce2.)
// ---------------------------------------------------------------------------
__global__ __launch_bounds__(256) void prep_kernel(const float* __restrict__ x,
                                                   const float* __restrict__ wpool,
                                                   const float* __restrict__ wwin,
                                                   const float* __restrict__ emb,
                                                   ushort* __restrict__ XbT,
                                                   ushort* __restrict__ wtH,
                                                   ushort* __restrict__ wtL,
                                                   ushort* __restrict__ eH,
                                                   ushort* __restrict__ eL) {
  const int b = blockIdx.x, tid = threadIdx.x;
  if (b < 10240) {            // XbT[j][m] = bf16(x[j>>5][m][j&31]), zero pad m>=NN
    const int j = b / 20, m = (b - j * 20) * 256 + tid;
    const int bb = j >> 5, c = j & 31;
    ushort v = 0;
    if (m < NN) v = f2bf(x[((size_t)bb * NN + m) * DINC + c]);
    XbT[(size_t)j * KPAD + m] = v;
  } else if (b < 11008) {     // wpool -> wtH/wtL[col'][d], col' = o*96+kk*32+i
    const int t = (b - 10240) * 256 + tid;    // 768*256 = 3072*64
    const int col = t >> 6, d = t & 63;
    const int o = col / 96, r2 = col - o * 96, kk = r2 >> 5, i = r2 & 31;
    const float v = wpool[(size_t)d * 3072 + kk * 1024 + i * 32 + o];
    const ushort h = f2bf(v);
    wtH[t] = h;                               // t == col*64 + d exactly
    wtL[t] = f2bf(v - bf2f(h));
  } else if (b < 11136) {     // wwin -> wtH/wtL[3072+col''][d], col'' = o*16+i
    const int t = (b - 11008) * 256 + tid;    // 128*256 = 512*64
    const int col = t >> 6, d = t & 63;
    const int o = col >> 4, i = col & 15;
    const float v = wwin[(size_t)d * 512 + i * 32 + o];
    const ushort h = f2bf(v);
    wtH[196608 + t] = h;                      // 196608 = 3072*64
    wtL[196608 + t] = f2bf(v - bf2f(h));
  } else {                    // emb -> bf16 hi + bf16 residual, rows padded to 5120
    const int t = (b - 11136) * 256 + tid;    // 1280*256 = 5120*64
    const int row = t >> 6;
    float v = 0.f;
    if (row < NN) v = emb[t];                 // t == row*64 + col exactly
    const ushort h = f2bf(v);
    eH[t] = h;
    eL[t] = f2bf(v - bf2f(h));
  }
}

// ---------------------------------------------------------------------------
// K1: fused A + exp, MFMA, no fp32 A intermediate, DIAG-SHIFT (R12).
// Normalization is deferred to the reduce kernels; any per-row constant c_m
// cancels exactly in e/sum — c_m = diag |e_m|^2 bounds the exponent. Each
// chunk-block recomputes the IDENTICAL diag from identical fragments
// (deterministic FP) -> all chunk sums of a row share one shift.
// R18: LDS-STAGED B-SIDE with global_load_lds + LDS dbuf. R23 (verified,
// -8 us): 8-way column split (grid 1256, 5 tiles/block) fixes the 2-round
// quantization at 2 blocks/CU. Chunk sums -> fp32[8] at 9472+2*ch.
// Per tile: stage(t+1) || MFMA+exp -> barrier -> stores (R22 ordering).
// Grid 1256 = 157 row-groups x 8 chunks of 640 cols; 5 tiles of 128 cols.
// ---------------------------------------------------------------------------
__global__ __launch_bounds__(256) void fused_A_softmax_kernel(const ushort* __restrict__ eH,
                                                              const ushort* __restrict__ eL,
                                                              ushort* __restrict__ P,
                                                              ushort* __restrict__ scr) {
  __shared__ __align__(16) ushort Ls[32768];  // 64 KB: [2 bufs][H 8192 | L 8192]
  const int tid = threadIdx.x;
  const int w = tid >> 6, l = tid & 63;
  const int fm = l & 15, kq = l >> 4;
  const int rg = blockIdx.x >> 3, ch = blockIdx.x & 7;  // grid 1256
  const int row0 = rg * 32;                   // rows 0..5023
  const int cbase = ch * 640;
  __shared__ float redL[4][32];
  __shared__ float diagL[32];

  // staging decode (mfma_gemm pattern): call q covers tile-rows q*32+(tid>>3),
  // chunk slot tid&7 (XOR-swizzled); LDS dst = wave-uniform + lane*16.
  const int rstg = tid >> 3;            // 0..31
  const int slot = tid & 7;
  ushort* lH = Ls + tid * 8;            // + buf*16384 + q*2048
  ushort* lL = Ls + 8192 + tid * 8;

  auto stage = [&](int buf, int t) {
    const int c0 = cbase + t * 128;
#pragma unroll
    for (int q = 0; q < 4; ++q) {
      const int r = q * 32 + rstg;
      const int cg = slot ^ (r & 7);
      gll16(eH + (size_t)(c0 + r) * 64 + cg * 8, lH + buf * 16384 + q * 2048);
    }
#pragma unroll
    for (int q = 0; q < 4; ++q) {
      const int r = q * 32 + rstg;
      const int cg = slot ^ (r & 7);
      gll16(eL + (size_t)(c0 + r) * 64 + cg * 8, lL + buf * 16384 + q * 2048);
    }
  };

  // A-side fragments (32 rows), loaded once: frag row = fm, k-slot = s*4+kq
  short8 aH[2][2], aL[2][2];
#pragma unroll
  for (int mf = 0; mf < 2; ++mf)
#pragma unroll
    for (int s = 0; s < 2; ++s) {
      const size_t o = (size_t)(row0 + mf * 16 + fm) * 64 + (s * 4 + kq) * 8;
      aH[mf][s] = *(const short8*)(eH + o);
      aL[mf][s] = *(const short8*)(eL + o);
    }

  stage(0, 0);   // tile-0 DMAs in flight under the diag reduction below

  // Per-row diag |e_row|^2 from the fragments: lane covers 16 of 64 elems
  // (k-slots kq and 4+kq); butterfly over the kq lane bits (16, 32).
#pragma unroll
  for (int mf = 0; mf < 2; ++mf) {
    float p = 0.f;
#pragma unroll
    for (int s = 0; s < 2; ++s)
#pragma unroll
      for (int j = 0; j < 8; ++j) {
        const float v = bf2f((ushort)aH[mf][s][j]) + bf2f((ushort)aL[mf][s][j]);
        p = fmaf(v, v, p);
      }
    p += __shfl_xor(p, 16);
    p += __shfl_xor(p, 32);
    if (w == 0 && kq == 0) diagL[mf * 16 + fm] = p;   // row mf*16+fm
  }
  __syncthreads();   // diagL visible AND tile-0 DMAs drained (vmcnt(0))
  float shift[2][4];
#pragma unroll
  for (int mf = 0; mf < 2; ++mf)
#pragma unroll
    for (int r = 0; r < 4; ++r) shift[mf][r] = diagL[mf * 16 + kq * 4 + r];

  float rs[2][4] = {};
  ushort* prow[2][4];
#pragma unroll
  for (int mf = 0; mf < 2; ++mf)
#pragma unroll
    for (int r = 0; r < 4; ++r) {
      const int gm = row0 + mf * 16 + kq * 4 + r;
      prow[mf][r] = (gm < NN) ? (P + (size_t)gm * 10000 + (gm & 1) * 16) : scr;
    }

  int cur = 0;
  for (int t = 0; t < 5; ++t) {
    if (t < 4) stage(cur ^ 1, t + 1);   // issue tile t+1 DMAs (overlap below)
    const ushort* H = Ls + cur * 16384;
    const ushort* L = H + 8192;
    const int c0 = cbase + t * 128;
    float4v acc[2][2] = {};
#pragma unroll
    for (int s = 0; s < 2; ++s) {
      short8 bh[2], bl[2];
#pragma unroll
      for (int nf = 0; nf < 2; ++nf) {
        const int row = w * 32 + nf * 16 + fm;      // local col within tile
        const int sl = (s * 4 + kq) ^ (fm & 7);
        bh[nf] = *(const short8*)(H + row * 64 + sl * 8);
        bl[nf] = *(const short8*)(L + row * 64 + sl * 8);
      }
#pragma unroll
      for (int mf = 0; mf < 2; ++mf)
#pragma unroll
        for (int nf = 0; nf < 2; ++nf) {
          acc[mf][nf] = __builtin_amdgcn_mfma_f32_16x16x32_bf16(aL[mf][s], bh[nf], acc[mf][nf], 0, 0, 0);
          acc[mf][nf] = __builtin_amdgcn_mfma_f32_16x16x32_bf16(aH[mf][s], bl[nf], acc[mf][nf], 0, 0, 0);
          acc[mf][nf] = __builtin_amdgcn_mfma_f32_16x16x32_bf16(aH[mf][s], bh[nf], acc[mf][nf], 0, 0, 0);
        }
    }
    // exp/VALU epilogue BEFORE the barrier (covers the in-flight DMAs);
    // values parked in statically-indexed regs.
    ushort ev[2][2][4];
#pragma unroll
    for (int nf = 0; nf < 2; ++nf) {
      const int col = c0 + w * 32 + nf * 16 + fm;
      const bool ok = col < NN;               // k-pad cols [5000,5120) -> exact 0
#pragma unroll
      for (int mf = 0; mf < 2; ++mf)
#pragma unroll
        for (int r = 0; r < 4; ++r) {
          const float v = fmaxf(acc[mf][nf][r], 0.f);   // relu
          const float e = ok ? __expf(v - shift[mf][r]) : 0.f;
          rs[mf][r] += e;
          ev[nf][mf][r] = f2bf(e);
        }
    }
    __builtin_amdgcn_sched_barrier(0);  // pin the exp VALU before the barrier
    if (t < 4) __syncthreads();         // drains aged DMAs + PREV tile's stores
    // stores AFTER the barrier: their drain is deferred to the next barrier.
#pragma unroll
    for (int nf = 0; nf < 2; ++nf) {
      const int col = c0 + w * 32 + nf * 16 + fm;
#pragma unroll
      for (int mf = 0; mf < 2; ++mf)
#pragma unroll
        for (int r = 0; r < 4; ++r)
          prow[mf][r][col] = ev[nf][mf][r];
    }
    cur ^= 1;
  }

  // chunk sums: shfl over the 16 fm-lanes, LDS over the 4 waves, write fp32
  // at row spare offset 9472 + 2*ch (ch = 0..7).
#pragma unroll
  for (int mf = 0; mf < 2; ++mf)
#pragma unroll
    for (int r = 0; r < 4; ++r) {
      float v = rs[mf][r];
#pragma unroll
      for (int msk = 1; msk < 16; msk <<= 1) v += __shfl_xor(v, msk);
      rs[mf][r] = v;
    }
  __syncthreads();           // redL region reuse barrier (after compute loop)
  if (fm == 0) {
#pragma unroll
    for (int mf = 0; mf < 2; ++mf)
#pragma unroll
      for (int r = 0; r < 4; ++r) redL[w][mf * 16 + kq * 4 + r] = rs[mf][r];
  }
  __syncthreads();
  if (w == 0 && fm == 0) {
#pragma unroll
    for (int mf = 0; mf < 2; ++mf)
#pragma unroll
      for (int r = 0; r < 4; ++r) {
        const int mm = mf * 16 + kq * 4 + r;
        const int gm = row0 + mm;
        if (gm < NN) {
          const float tot = redL[0][mm] + redL[1][mm] + redL[2][mm] + redL[3][mm];
          *(float*)(P + (size_t)gm * 10000 + 9472 + 2 * ch) = tot;
        }
      }
  }
}

// ---------------------------------------------------------------------------
// K3/K5: bf16 MFMA GEMM. BM=BN=128, BK=64, 256 thr = 4 waves (2x2 of 64x64).
// R25: 32x32x16 MFMA (was 16x16x32). The GEMM sits at the 2-phase template
// ceiling (626 TF); within the template the remaining lever is per-MFMA
// efficiency: 32x32x16 µbench 2382-2495 TF vs 16x16x32's 2075 (~20% better
// cyc/FLOP) and HALF the MFMA instructions (16/iter/wave vs 32; wave tile
// 64x64 = 2x2 of 32x32, K=64 = 4 k-steps). Operand layouts (AMD matrix-core
// pattern, C/D HW-verified m74/m101): A/B lane = i + 32*(k div 8), elem =
// k mod 8 -> lane reads 8 consecutive k of row (l&31) at chunk ks*2+(l>>5);
// C/D col = lane&31, row = (reg&3)+8*(reg>>2)+4*(lane>>5). Same LDS layout,
// same global-side XOR swizzle (slot = chunk^(row&7), row&7 = l&7 -> same
// conflict-free pattern), same 16 ds_reads/iter. Staging/pipeline/decode
// byte-identical to the verified R14 config.
// Split-K=8 (k-chunk 640 = 10 iters), 1D grid 1280.
// R19 (verified): YB-OUTER XCD-AWARE DECODE — yb = id>>5, xb = (id>>3)&3,
// zb = id&7 keeps XCD = zb but runs yb-major with xb inner: co-resident set
// per XCD = 16 yb x 4 xb -> A 2.6 MB + B-slice 0.65 MB < 4 MB L2.
// R13: 2-phase dbuf pipeline (stage k+1 before compute k; one barrier/iter).
// R9 DMA locality: each wave-instr loads 8 ROWS x 128 B.
// ---------------------------------------------------------------------------
__global__ __launch_bounds__(256) void mfma_gemm_kernel(const ushort* __restrict__ Pm,
                                                        const ushort* __restrict__ Bt,
                                                        ushort* __restrict__ Pp) {
  __shared__ __align__(16) ushort Ls[32768];  // [2 bufs][As 8192 | Bs 8192]
  const int tid = threadIdx.x;
  const int w = tid >> 6, l = tid & 63;
  const int wm = w >> 1, wn = w & 1;
  const int id = blockIdx.x;            // 0..1279
  const int yb = id >> 5;               // row tile 0..39  (OUTER)
  const int xb = (id >> 3) & 3;         // col tile 0..3   (inner)
  const int zb = id & 7;                // k-chunk 0..7 (= XCD)
  const int row0 = yb * 128, col0 = xb * 128;
  const int kbase = zb * 640;
  // staging: call q covers rows q*32+(tid>>3), chunk slot tid&7 (XOR-swizzled)
  const int rstg = tid >> 3;            // 0..31
  const int slot = tid & 7;
  const ushort* gAq[4];
  const ushort* gBq[4];
#pragma unroll
  for (int q = 0; q < 4; ++q) {
    const int r = q * 32 + rstg;
    const int cg = slot ^ (r & 7);      // global k-chunk this lane fetches
    const int arow = row0 + r;
    gAq[q] = Pm + (size_t)arow * 10000 + (arow & 1) * 16 + kbase + cg * 8;
    gBq[q] = Bt + (size_t)(col0 + r) * KPAD + kbase + cg * 8;
  }
  ushort* lA = Ls + tid * 8;            // + buf*16384 + q*2048 (row-major exact)
  ushort* lB = Ls + 8192 + tid * 8;
  float16v acc[2][2] = {};              // 2x2 of 32x32 tiles, 16 f32/lane each

  const int rA = l & 31;                // operand row (A) / col (B) within 32-tile
  const int hk = l >> 5;                // k-half selector (8-elem chunks)

  auto stage = [&](int buf) {
#pragma unroll
    for (int q = 0; q < 4; ++q) gll16(gAq[q], lA + buf * 16384 + q * 2048);
#pragma unroll
    for (int q = 0; q < 4; ++q) gll16(gBq[q], lB + buf * 16384 + q * 2048);
#pragma unroll
    for (int q = 0; q < 4; ++q) { gAq[q] += 64; gBq[q] += 64; }
  };
  auto compute = [&](int buf) {
    const ushort* As = Ls + buf * 16384;
    const ushort* Bs = As + 8192;
#pragma unroll
    for (int ks = 0; ks < 4; ++ks) {    // K=64 in 4 steps of 16
      const int chunk = ks * 2 + hk;    // 8-ushort chunk within the 64-k row
      short8 a[2], b[2];
#pragma unroll
      for (int mt = 0; mt < 2; ++mt) {
        const int row = wm * 64 + mt * 32 + rA;
        const int sl = chunk ^ (row & 7);
        a[mt] = *(const short8*)(As + row * 64 + sl * 8);
      }
#pragma unroll
      for (int nt = 0; nt < 2; ++nt) {
        const int row = wn * 64 + nt * 32 + rA;   // B stored [col][k]
        const int sl = chunk ^ (row & 7);
        b[nt] = *(const short8*)(Bs + row * 64 + sl * 8);
      }
#pragma unroll
      for (int mt = 0; mt < 2; ++mt)
#pragma unroll
        for (int nt = 0; nt < 2; ++nt)
          acc[mt][nt] = __builtin_amdgcn_mfma_f32_32x32x16_bf16(a[mt], b[nt], acc[mt][nt], 0, 0, 0);
    }
  };

  stage(0);          // prologue: tile 0 -> buf 0
  __syncthreads();   // vmcnt(0) drain + barrier: buf0 ready
  int cur = 0;
  for (int kt = 0; kt < 9; ++kt) {
    stage(cur ^ 1);  // issue tile kt+1 DMAs (async, overlap with MFMAs below)
    compute(cur);
    __syncthreads(); // drains this iter's DMAs (tile kt+1 ready) + all waves
    cur ^= 1;        // done reading buf cur -> safe to overwrite next iter
  }
  compute(cur);      // last tile, no prefetch

  // epilogue: bf16 partials into the P rows' free halves.
  // C/D 32x32 layout: col = lane&31, row = (reg&3) + 8*(reg>>2) + 4*(lane>>5).
  const int cb = col0 + wn * 64 + rA;
  const int zoff = 5160 + zb * 512;
#pragma unroll
  for (int mt = 0; mt < 2; ++mt)
#pragma unroll
    for (int reg = 0; reg < 16; ++reg) {
      const int rrow = (reg & 3) + 8 * (reg >> 2) + 4 * hk;
      const int gm = row0 + wm * 64 + mt * 32 + rrow;
      if (gm < NN) {
        ushort* prow = Pp + (size_t)gm * 10000 + zoff + cb;
#pragma unroll
        for (int nt = 0; nt < 2; ++nt) prow[nt * 32] = f2bf(acc[mt][nt][reg]);
      }
    }
}

// ---------------------------------------------------------------------------
// K4/K6: sum 8 bf16 split-K partials, SCALE by the row's deferred softmax
// inverse sum (1 / sum of the 8 fp32 chunk sums at P-row ushort offset 9472,
// two 16B-aligned float4s) -> Yf fp32 [5000][512]; optionally also Yt bf16
// [512][KPAD] (transposed, zero pad m in [5000,5120)). Grid (8,80).
// ---------------------------------------------------------------------------
__global__ __launch_bounds__(256) void reduce_kernel(const ushort* __restrict__ Pp,
                                                     float* __restrict__ Yf,
                                                     ushort* __restrict__ Yt,
                                                     int writeT) {
  const int m0 = blockIdx.y * 64, n0 = blockIdx.x * 64;
  __shared__ __align__(16) ushort Lt[64][80];  // [n][m]
  const int tid = threadIdx.x;
  const int mi = tid >> 4, nl4 = (tid & 15) << 2;
#pragma unroll
  for (int s = 0; s < 4; ++s) {
    const int m = m0 + mi + s * 16;
    float4 sum = make_float4(0.f, 0.f, 0.f, 0.f);
    if (m < NN) {
      const ushort* pr = Pp + (size_t)m * 10000 + 5160 + n0 + nl4;
#pragma unroll
      for (int z = 0; z < 8; ++z) {
        ushort4 u = *(const ushort4*)(pr + z * 512);
        sum.x += bf2f(u.x); sum.y += bf2f(u.y);
        sum.z += bf2f(u.z); sum.w += bf2f(u.w);
      }
      const float4 s4a = *(const float4*)(Pp + (size_t)m * 10000 + 9472);
      const float4 s4b = *(const float4*)(Pp + (size_t)m * 10000 + 9480);
      const float sc = 1.f / (s4a.x + s4a.y + s4a.z + s4a.w +
                              s4b.x + s4b.y + s4b.z + s4b.w);
      sum.x *= sc; sum.y *= sc; sum.z *= sc; sum.w *= sc;
      *(float4*)(Yf + (size_t)m * BC + n0 + nl4) = sum;
    }
    if (writeT) {
      const int ml = mi + s * 16;
      Lt[nl4 + 0][ml] = f2bf(sum.x);
      Lt[nl4 + 1][ml] = f2bf(sum.y);
      Lt[nl4 + 2][ml] = f2bf(sum.z);
      Lt[nl4 + 3][ml] = f2bf(sum.w);
    }
  }
  if (writeT) {
    __syncthreads();
#pragma unroll
    for (int i = 0; i < 2; ++i) {
      const int g = tid + i * 256;
      const int nl = g >> 3, gi = g & 7;
      *(uint4*)(Yt + (size_t)(n0 + nl) * KPAD + m0 + gi * 8) =
          *(const uint4*)(&Lt[nl][gi * 8]);
    }
  }
}

// ---------------------------------------------------------------------------
// K7: Wt/wwt via MFMA (R20/R21). A-frags built from the fp32 emb INPUT on
// the fly (hi/lo split, deterministic) — NOT from embH/embL, which overlay
// Y1f and are DEAD after reduce1. C[gm][col] = sum_d emb[gm][d]*wt[col][d],
// col in [0,3584): [0,3072) -> Wt (stride 3072), [3072,3584) -> wwt (512).
// Grid 157 x 14 col-chunks of 256 = 2198 blocks. B-frags direct from
// L2-resident wtH/wtL (448 KB each, untouched between prep and here).
// 48 MFMAs/block, 3-term hi/lo. Pad rows zero-guarded / store-guarded.
// ---------------------------------------------------------------------------
__global__ __launch_bounds__(256) void emb_wt_mfma_kernel(const float* __restrict__ emb,
                                                          const ushort* __restrict__ wtH,
                                                          const ushort* __restrict__ wtL,
                                                          ushort* __restrict__ Wt,
                                                          ushort* __restrict__ wwt) {
  const int tid = threadIdx.x;
  const int w = tid >> 6, l = tid & 63;
  const int fm = l & 15, kq = l >> 4;
  const int rg = blockIdx.x / 14, cc = blockIdx.x % 14;  // 157 x 14
  const int row0 = rg * 32;                   // rows 0..5023
  const int c0 = cc * 256 + w * 64;           // wave's col base in [0,3584)

  short8 aH[2][2], aL[2][2];
#pragma unroll
  for (int mf = 0; mf < 2; ++mf) {
    const int gr = row0 + mf * 16 + fm;
#pragma unroll
    for (int s = 0; s < 2; ++s) {
      short8 h = {}, lo = {};
      if (gr < NN) {
        const float* p = emb + (size_t)gr * EDIM + (s * 4 + kq) * 8;
        const float4 v0 = *(const float4*)p, v1 = *(const float4*)(p + 4);
        const float vv[8] = {v0.x, v0.y, v0.z, v0.w, v1.x, v1.y, v1.z, v1.w};
#pragma unroll
        for (int j = 0; j < 8; ++j) {
          const ushort hh = f2bf(vv[j]);
          h[j] = (short)hh;
          lo[j] = (short)f2bf(vv[j] - bf2f(hh));
        }
      }
      aH[mf][s] = h;
      aL[mf][s] = lo;
    }
  }

  float4v acc[2][4] = {};
#pragma unroll
  for (int s = 0; s < 2; ++s) {
    short8 bh[4], bl[4];
#pragma unroll
    for (int nf = 0; nf < 4; ++nf) {
      const size_t o = (size_t)(c0 + nf * 16 + fm) * 64 + (s * 4 + kq) * 8;
      bh[nf] = *(const short8*)(wtH + o);
      bl[nf] = *(const short8*)(wtL + o);
    }
#pragma unroll
    for (int mf = 0; mf < 2; ++mf)
#pragma unroll
      for (int nf = 0; nf < 4; ++nf) {
        acc[mf][nf] = __builtin_amdgcn_mfma_f32_16x16x32_bf16(aL[mf][s], bh[nf], acc[mf][nf], 0, 0, 0);
        acc[mf][nf] = __builtin_amdgcn_mfma_f32_16x16x32_bf16(aH[mf][s], bl[nf], acc[mf][nf], 0, 0, 0);
        acc[mf][nf] = __builtin_amdgcn_mfma_f32_16x16x32_bf16(aH[mf][s], bh[nf], acc[mf][nf], 0, 0, 0);
      }
  }
#pragma unroll
  for (int nf = 0; nf < 4; ++nf) {
    const int col = c0 + nf * 16 + fm;
#pragma unroll
    for (int mf = 0; mf < 2; ++mf)
#pragma unroll
      for (int r = 0; r < 4; ++r) {
        const int gm = row0 + mf * 16 + kq * 4 + r;
        if (gm < NN) {
          const ushort v = f2bf(acc[mf][nf][r]);
          if (col < 3072) Wt[(size_t)gm * 3072 + col] = v;
          else            wwt[(size_t)gm * 512 + (col - 3072)] = v;
        }
      }
  }
}

// ---------------------------------------------------------------------------
// K9: biasN fp32 [5000][64] = emb @ bias_pool.
// ---------------------------------------------------------------------------
__global__ __launch_bounds__(256) void emb_gemm_kernel(const float* __restrict__ Ae,
                                                       const float* __restrict__ Bw,
                                                       float* __restrict__ C,
                                                       int M, int Nc) {
  __shared__ float Aet[EDIM][33];
  __shared__ __align__(16) float Bs[EDIM][64];
  const int row0 = blockIdx.y * 32, col0 = blockIdx.x * 64;
  const int tid = threadIdx.x;
  for (int i = tid; i < 512; i += 256) {
    const int r = i >> 4, d4 = (i & 15) << 2;
    const int gm = row0 + r;
    float4 v = make_float4(0.f, 0.f, 0.f, 0.f);
    if (gm < M) v = *(const float4*)(Ae + (size_t)gm * EDIM + d4);
    Aet[d4 + 0][r] = v.x; Aet[d4 + 1][r] = v.y; Aet[d4 + 2][r] = v.z; Aet[d4 + 3][r] = v.w;
  }
  for (int i = tid; i < 1024; i += 256) {
    const int br = i >> 4, bc = (i & 15) << 2;
    if (bc < Nc) *(float4*)&Bs[br][bc] = *(const float4*)(Bw + (size_t)br * Nc + bc);
  }
  __syncthreads();
  const int ty = tid >> 4, tx = tid & 15;
  float acc[2][4] = {};
#pragma unroll 8
  for (int d = 0; d < EDIM; ++d) {
    const float a0 = Aet[d][ty * 2], a1 = Aet[d][ty * 2 + 1];
    const float4 b4 = *(const float4*)&Bs[d][tx << 2];
    acc[0][0] = fmaf(a0, b4.x, acc[0][0]); acc[0][1] = fmaf(a0, b4.y, acc[0][1]);
    acc[0][2] = fmaf(a0, b4.z, acc[0][2]); acc[0][3] = fmaf(a0, b4.w, acc[0][3]);
    acc[1][0] = fmaf(a1, b4.x, acc[1][0]); acc[1][1] = fmaf(a1, b4.y, acc[1][1]);
    acc[1][2] = fmaf(a1, b4.z, acc[1][2]); acc[1][3] = fmaf(a1, b4.w, acc[1][3]);
  }
#pragma unroll
  for (int r = 0; r < 2; ++r) {
    const int gm = row0 + ty * 2 + r;
    if (gm >= M) continue;
    float4 o;
    o.x = acc[r][0]; o.y = acc[r][1]; o.z = acc[r][2]; o.w = acc[r][3];
    *(float4*)(C + (size_t)gm * Nc + col0 + (tx << 2)) = o;
  }
}

// ---------------------------------------------------------------------------
// K10: xwc[b, n, i] = sum_t T[t] * x_window[b, t, n, i]
// (launched AFTER reduce2: xwc buffer overlays the dead A/P region)
// ---------------------------------------------------------------------------
__global__ __launch_bounds__(256) void window_combine_kernel(const float* __restrict__ xw,
                                                             const float* __restrict__ T,
                                                             float* __restrict__ out) {
  const int idx = blockIdx.x * 256 + threadIdx.x;
  if (idx >= BB * NN * 16) return;
  const int b = idx / (NN * 16);
  const int rem = idx - b * (NN * 16);
  float acc = 0.f;
#pragma unroll
  for (int t = 0; t < LAGN; ++t)
    acc = fmaf(T[t], xw[(size_t)(b * LAGN + t) * (NN * 16) + rem], acc);
  out[idx] = acc;
}

// ---------------------------------------------------------------------------
// K11: MFMA fusion. One wave per node: gconv (6 MFMAs) + wconv (2 MFMAs),
// LN via 16-lane butterflies on the C-layout, concat + bias.
// ---------------------------------------------------------------------------
__global__ __launch_bounds__(256) void fuse_mfma_kernel(const float* __restrict__ x,
                                                        const float* __restrict__ Y1f,
                                                        const float* __restrict__ Y2f,
                                                        const ushort* __restrict__ Wt,
                                                        const ushort* __restrict__ wwt,
                                                        const float* __restrict__ biasN,
                                                        const float* __restrict__ xwc,
                                                        const float* __restrict__ ln1w,
                                                        const float* __restrict__ ln1b,
                                                        const float* __restrict__ ln2w,
                                                        const float* __restrict__ ln2b,
                                                        float* __restrict__ out) {
  const int tid = threadIdx.x;
  const int n = blockIdx.x * 4 + (tid >> 6);  // grid 1250*4 = 5000 exact
  const int l = tid & 63, fm = l & 15, kq = l >> 4;
  const short8 ax = cvt8(x + ((size_t)fm * NN + n) * DINC + kq * 8);
  const short8 a1 = cvt8(Y1f + (size_t)n * BC + fm * 32 + kq * 8);
  const short8 a2 = cvt8(Y2f + (size_t)n * BC + fm * 32 + kq * 8);
  short8 aw = {};
  if (kq < 2) aw = cvt8(xwc + ((size_t)fm * NN + n) * 16 + kq * 8);
  const ushort* wn = Wt + (size_t)n * 3072;
  const ushort* wwn = wwt + (size_t)n * 512;
  float4v accG[2] = {}, accW[2] = {};
#pragma unroll
  for (int t = 0; t < 2; ++t) {
    const int ob = (t * 16 + fm) * 96 + kq * 8;
    const short8 b0 = *(const short8*)(wn + ob);
    const short8 b1 = *(const short8*)(wn + ob + 32);
    const short8 b2 = *(const short8*)(wn + ob + 64);
    accG[t] = __builtin_amdgcn_mfma_f32_16x16x32_bf16(ax, b0, accG[t], 0, 0, 0);
    accG[t] = __builtin_amdgcn_mfma_f32_16x16x32_bf16(a1, b1, accG[t], 0, 0, 0);
    accG[t] = __builtin_amdgcn_mfma_f32_16x16x32_bf16(a2, b2, accG[t], 0, 0, 0);
    short8 bw = {};
    if (kq < 2) bw = *(const short8*)(wwn + (t * 16 + fm) * 16 + kq * 8);
    accW[t] = __builtin_amdgcn_mfma_f32_16x16x32_bf16(aw, bw, accW[t], 0, 0, 0);
  }
  const float w1a = ln1w[fm], w1b = ln1w[16 + fm];
  const float c1a = ln1b[fm], c1b = ln1b[16 + fm];
  const float w2a = ln2w[fm], w2b = ln2w[16 + fm];
  const float c2a = ln2b[fm], c2b = ln2b[16 + fm];
  const float* bn = biasN + (size_t)n * 64;
  const float bga = bn[fm], bgb = bn[16 + fm];
  const float bwa = bn[32 + fm], bwb = bn[48 + fm];
#pragma unroll
  for (int r = 0; r < 4; ++r) {
    const int b = kq * 4 + r;
    const float g0 = accG[0][r], g1 = accG[1][r];
    float s1 = g0 + g1, s2 = g0 * g0 + g1 * g1;
#pragma unroll
    for (int m = 1; m < 16; m <<= 1) { s1 += __shfl_xor(s1, m); s2 += __shfl_xor(s2, m); }
    const float mu = s1 * 0.03125f;
    const float rs = rsqrtf(s2 * 0.03125f - mu * mu + 1e-5f);
    const float h0 = accW[0][r], h1 = accW[1][r];
    float t1 = h0 + h1, t2 = h0 * h0 + h1 * h1;
#pragma unroll
    for (int m = 1; m < 16; m <<= 1) { t1 += __shfl_xor(t1, m); t2 += __shfl_xor(t2, m); }
    const float mu2 = t1 * 0.03125f;
    const float rs2 = rsqrtf(t2 * 0.03125f - mu2 * mu2 + 1e-5f);
    float* op = out + ((size_t)b * NN + n) * 64;
    op[fm]      = (g0 - mu) * rs * w1a + c1a + bga;
    op[16 + fm] = (g1 - mu) * rs * w1b + c1b + bgb;
    op[32 + fm] = (h0 - mu2) * rs2 * w2a + c2a + bwa;
    op[48 + fm] = (h1 - mu2) * rs2 * w2b + c2b + bwb;
  }
}

// ---------------------------------------------------------------------------
// Workspace map (fp32 slots), high-water 30,410,816 floats = 121.6 MB:
//   [0, 25M)              P bf16 rows (fused_A_softmax output; row m =
//                         ushorts [m*10000+(m&1)*16, +5120) P~,
//                         [m*10000+5160, +4096) 8 bf16 split-K partial slabs,
//                         chunk sums fp32[8] at ushort offset m*10000+9472)
//                         -> after reduce2: overlaid by Wt/wwt/biasN/xwc
//   [25.0M, 26.31072M)    XbT bf16 [512][5120]   (dead after GEMM1)
//   [26.31072M,27.62144M) Y1t bf16 [512][5120]   (dead after GEMM2)
//   [25.0M, 27.56M)       Y2f fp32 (reduce2 output, overlays XbT+Y1t)
//   [27.62144M,30.18144M) Y1f fp32; BEFORE reduce1 this region also hosts:
//       [27621440,27785280)  embH bf16 [5120][64]  (DEAD after reduce1! —
//       [27785280,27949120)  embL bf16 [5120][64]   only fused_A may read)
//       [27949120,27951680)  ascr — 5120-ushort tail-row store scratch
//   [30181440,30296128)   wtH bf16 [3584][64] (transposed hi pools; live
//   [30296128,30410816)   wtL bf16 [3584][64]  from prep to emb_wt_mfma)
// ---------------------------------------------------------------------------
extern "C" void kernel_launch(void* const* d_in, const int* in_sizes, int n_in,
                              void* d_out, int out_size, void* d_ws, size_t ws_size,
                              hipStream_t stream) {
  const float* x     = (const float*)d_in[0];
  const float* xwin  = (const float*)d_in[1];
  const float* emb   = (const float*)d_in[2];
  const float* wpool = (const float*)d_in[3];
  const float* wwin  = (const float*)d_in[4];
  const float* bpool = (const float*)d_in[5];
  const float* T     = (const float*)d_in[6];
  const float* ln1w  = (const float*)d_in[7];
  const float* ln1b  = (const float*)d_in[8];
  const float* ln2w  = (const float*)d_in[9];
  const float* ln2b  = (const float*)d_in[10];
  float* out = (float*)d_out;
  float* ws = (float*)d_ws;

  ushort* P    = (ushort*)ws;
  ushort* XbT  = (ushort*)(ws + 25000000);
  ushort* Y1t  = (ushort*)(ws + 26310720);
  float*  Y1f  = ws + 27621440;
  float*  Y2f  = ws + 25000000;        // overlays XbT+Y1t after GEMM2
  ushort* embH = (ushort*)(ws + 27621440);   // overlays Y1f until reduce1
  ushort* embL = (ushort*)(ws + 27785280);
  ushort* ascr = (ushort*)(ws + 27949120);   // 5120-ushort tail scratch
  ushort* Wt    = (ushort*)ws;         // [5000][3072] bf16, overlays P after reduce2
  ushort* wwt   = (ushort*)(ws + 15360000);  // [5000][512] bf16
  float*  biasN = ws + 17920000;
  float*  xwc   = ws + 18240000;       // overlays P rows — write after reduce2!
  ushort* wtH   = (ushort*)(ws + 30181440);  // [3584][64] bf16 hi
  ushort* wtL   = (ushort*)(ws + 30296128);  // [3584][64] bf16 lo

  prep_kernel<<<12416, 256, 0, stream>>>(x, wpool, wwin, emb, XbT, wtH, wtL, embH, embL);
  fused_A_softmax_kernel<<<1256, 256, 0, stream>>>(embH, embL, P, ascr);
  mfma_gemm_kernel<<<1280, 256, 0, stream>>>(P, XbT, P);
  reduce_kernel<<<dim3(8, 80), 256, 0, stream>>>(P, Y1f, Y1t, 1);
  mfma_gemm_kernel<<<1280, 256, 0, stream>>>(P, Y1t, P);
  reduce_kernel<<<dim3(8, 80), 256, 0, stream>>>(P, Y2f, (ushort*)nullptr, 0);
  emb_wt_mfma_kernel<<<2198, 256, 0, stream>>>(emb, wtH, wtL, Wt, wwt);
  emb_gemm_kernel<<<dim3(1, 157), 256, 0, stream>>>(emb, bpool, biasN, NN, 64);
  window_combine_kernel<<<(BB * NN * 16 + 255) / 256, 256, 0, stream>>>(xwin, T, xwc);
  fuse_mfma_kernel<<<1250, 256, 0, stream>>>(x, Y1f, Y2f, Wt, wwt, biasN, xwc,
                                             ln1w, ln1b, ln2w, ln2b, out);
}

// Round 19
// 322.084 us; speedup vs baseline: 1.0319x; 1.0281x over previous
//
#include <hip/hip_runtime.h>
#include <hip/hip_bf16.h>

// Problem constants (reference setup_inputs)
#define NN   5000   // nodes
#define EDIM 64     // embedding dim
#define DINC 32     // DIN
#define BB   16     // batch
#define LAGN 12     // LAG
#define BC   512    // BB*DINC
#define KPAD 5120   // k-extent padded to 128-tile multiple (zeros in [5000,5120))

typedef __attribute__((ext_vector_type(8))) short short8;   // 8 bf16 = 4 VGPRs
typedef __attribute__((ext_vector_type(4))) float float4v;  // MFMA 16x16 C/D

static __device__ __forceinline__ ushort f2bf(float x) {
  __hip_bfloat16 h = __float2bfloat16(x);
  return *reinterpret_cast<ushort*>(&h);
}
static __device__ __forceinline__ float bf2f(ushort u) {
  unsigned int x = ((unsigned int)u) << 16;
  return __uint_as_float(x);
}
static __device__ __forceinline__ short8 cvt8(const float* p) {  // 8 floats -> bf16x8
  const float4 v0 = *(const float4*)p, v1 = *(const float4*)(p + 4);
  short8 r;
  r[0] = (short)f2bf(v0.x); r[1] = (short)f2bf(v0.y);
  r[2] = (short)f2bf(v0.z); r[3] = (short)f2bf(v0.w);
  r[4] = (short)f2bf(v1.x); r[5] = (short)f2bf(v1.y);
  r[6] = (short)f2bf(v1.z); r[7] = (short)f2bf(v1.w);
  return r;
}

// async global->LDS DMA, 16 B per lane; LDS dst is wave-uniform base + lane*16.
static __device__ __forceinline__ void gll16(const ushort* g, ushort* l) {
  __builtin_amdgcn_global_load_lds(
      (const __attribute__((address_space(1))) void*)g,
      (__attribute__((address_space(3))) void*)l, 16, 0, 0);
}

// P row m (bf16) lives at ushort offset m*10000 + (m&1)*16  -> 64B-aligned rows.
// Split-K partial slab z for row m: ushort offset m*10000 + 5160 + z*512.
// Softmax chunk partial sums fp32[8] for row m: ushort offset m*10000 + 9472
// (16B-aligned, 32 B; spare region [9256,10000) of each row; GEMM epilogue
// tops out at 9255). reduce_kernel sums the 8 and multiplies by reciprocal.

// ---------------------------------------------------------------------------
// K0: merged prep — transpose_xb | wt hi/lo transposed pools | emb hi/lo bf16.
// R20: wpool/wwin emitted TRANSPOSED + hi/lo bf16 (wtH/wtL[col'][64]) so the
// Wt/wwt GEMM runs on MFMA with the fused_A B-fragment read pattern.
// (xwc NOT here: its buffer overlays the A/P region — write after reduce2.)
// ---------------------------------------------------------------------------
__global__ __launch_bounds__(256) void prep_kernel(const float* __restrict__ x,
                                                   const float* __restrict__ wpool,
                                                   const float* __restrict__ wwin,
                                                   const float* __restrict__ emb,
                                                   ushort* __restrict__ XbT,
                                                   ushort* __restrict__ wtH,
                                                   ushort* __restrict__ wtL,
                                                   ushort* __restrict__ eH,
                                                   ushort* __restrict__ eL) {
  const int b = blockIdx.x, tid = threadIdx.x;
  if (b < 10240) {            // XbT[j][m] = bf16(x[j>>5][m][j&31]), zero pad m>=NN
    const int j = b / 20, m = (b - j * 20) * 256 + tid;
    const int bb = j >> 5, c = j & 31;
    ushort v = 0;
    if (m < NN) v = f2bf(x[((size_t)bb * NN + m) * DINC + c]);
    XbT[(size_t)j * KPAD + m] = v;
  } else if (b < 11008) {     // wpool -> wtH/wtL[col'][d], col' = o*96+kk*32+i
    const int t = (b - 10240) * 256 + tid;    // 768*256 = 3072*64
    const int col = t >> 6, d = t & 63;
    const int o = col / 96, r2 = col - o * 96, kk = r2 >> 5, i = r2 & 31;
    const float v = wpool[(size_t)d * 3072 + kk * 1024 + i * 32 + o];
    const ushort h = f2bf(v);
    wtH[t] = h;                               // t == col*64 + d exactly
    wtL[t] = f2bf(v - bf2f(h));
  } else if (b < 11136) {     // wwin -> wtH/wtL[3072+col''][d], col'' = o*16+i
    const int t = (b - 11008) * 256 + tid;    // 128*256 = 512*64
    const int col = t >> 6, d = t & 63;
    const int o = col >> 4, i = col & 15;
    const float v = wwin[(size_t)d * 512 + i * 32 + o];
    const ushort h = f2bf(v);
    wtH[196608 + t] = h;                      // 196608 = 3072*64
    wtL[196608 + t] = f2bf(v - bf2f(h));
  } else {                    // emb -> bf16 hi + bf16 residual, rows padded to 5120
    const int t = (b - 11136) * 256 + tid;    // 1280*256 = 5120*64
    const int row = t >> 6;
    float v = 0.f;
    if (row < NN) v = emb[t];                 // t == row*64 + col exactly
    const ushort h = f2bf(v);
    eH[t] = h;
    eL[t] = f2bf(v - bf2f(h));
  }
}

// ---------------------------------------------------------------------------
// K1: fused A + exp, MFMA, no fp32 A intermediate, DIAG-SHIFT (R12).
// Normalization is deferred to the reduce kernels; any per-row constant c_m
// cancels exactly in e/sum — c_m = diag |e_m|^2 bounds the exponent. Each
// chunk-block recomputes the IDENTICAL diag from identical fragments
// (deterministic FP) -> all chunk sums of a row share one shift.
// R18: LDS-STAGED B-SIDE with global_load_lds + LDS dbuf. R23 (verified,
// -8 us): 8-way column split (grid 1256, 5 tiles/block) fixes the 2-round
// quantization at 2 blocks/CU. Chunk sums -> fp32[8] at 9472+2*ch.
// Per tile: stage(t+1) || MFMA+exp -> barrier -> stores (R22 ordering).
// Grid 1256 = 157 row-groups x 8 chunks of 640 cols; 5 tiles of 128 cols.
// ---------------------------------------------------------------------------
__global__ __launch_bounds__(256) void fused_A_softmax_kernel(const ushort* __restrict__ eH,
                                                              const ushort* __restrict__ eL,
                                                              ushort* __restrict__ P,
                                                              ushort* __restrict__ scr) {
  __shared__ __align__(16) ushort Ls[32768];  // 64 KB: [2 bufs][H 8192 | L 8192]
  const int tid = threadIdx.x;
  const int w = tid >> 6, l = tid & 63;
  const int fm = l & 15, kq = l >> 4;
  const int rg = blockIdx.x >> 3, ch = blockIdx.x & 7;  // grid 1256
  const int row0 = rg * 32;                   // rows 0..5023
  const int cbase = ch * 640;
  __shared__ float redL[4][32];
  __shared__ float diagL[32];

  // staging decode (mfma_gemm pattern): call q covers tile-rows q*32+(tid>>3),
  // chunk slot tid&7 (XOR-swizzled); LDS dst = wave-uniform + lane*16.
  const int rstg = tid >> 3;            // 0..31
  const int slot = tid & 7;
  ushort* lH = Ls + tid * 8;            // + buf*16384 + q*2048
  ushort* lL = Ls + 8192 + tid * 8;

  auto stage = [&](int buf, int t) {
    const int c0 = cbase + t * 128;
#pragma unroll
    for (int q = 0; q < 4; ++q) {
      const int r = q * 32 + rstg;
      const int cg = slot ^ (r & 7);
      gll16(eH + (size_t)(c0 + r) * 64 + cg * 8, lH + buf * 16384 + q * 2048);
    }
#pragma unroll
    for (int q = 0; q < 4; ++q) {
      const int r = q * 32 + rstg;
      const int cg = slot ^ (r & 7);
      gll16(eL + (size_t)(c0 + r) * 64 + cg * 8, lL + buf * 16384 + q * 2048);
    }
  };

  // A-side fragments (32 rows), loaded once: frag row = fm, k-slot = s*4+kq
  short8 aH[2][2], aL[2][2];
#pragma unroll
  for (int mf = 0; mf < 2; ++mf)
#pragma unroll
    for (int s = 0; s < 2; ++s) {
      const size_t o = (size_t)(row0 + mf * 16 + fm) * 64 + (s * 4 + kq) * 8;
      aH[mf][s] = *(const short8*)(eH + o);
      aL[mf][s] = *(const short8*)(eL + o);
    }

  stage(0, 0);   // tile-0 DMAs in flight under the diag reduction below

  // Per-row diag |e_row|^2 from the fragments: lane covers 16 of 64 elems
  // (k-slots kq and 4+kq); butterfly over the kq lane bits (16, 32).
#pragma unroll
  for (int mf = 0; mf < 2; ++mf) {
    float p = 0.f;
#pragma unroll
    for (int s = 0; s < 2; ++s)
#pragma unroll
      for (int j = 0; j < 8; ++j) {
        const float v = bf2f((ushort)aH[mf][s][j]) + bf2f((ushort)aL[mf][s][j]);
        p = fmaf(v, v, p);
      }
    p += __shfl_xor(p, 16);
    p += __shfl_xor(p, 32);
    if (w == 0 && kq == 0) diagL[mf * 16 + fm] = p;   // row mf*16+fm
  }
  __syncthreads();   // diagL visible AND tile-0 DMAs drained (vmcnt(0))
  float shift[2][4];
#pragma unroll
  for (int mf = 0; mf < 2; ++mf)
#pragma unroll
    for (int r = 0; r < 4; ++r) shift[mf][r] = diagL[mf * 16 + kq * 4 + r];

  float rs[2][4] = {};
  ushort* prow[2][4];
#pragma unroll
  for (int mf = 0; mf < 2; ++mf)
#pragma unroll
    for (int r = 0; r < 4; ++r) {
      const int gm = row0 + mf * 16 + kq * 4 + r;
      prow[mf][r] = (gm < NN) ? (P + (size_t)gm * 10000 + (gm & 1) * 16) : scr;
    }

  int cur = 0;
  for (int t = 0; t < 5; ++t) {
    if (t < 4) stage(cur ^ 1, t + 1);   // issue tile t+1 DMAs (overlap below)
    const ushort* H = Ls + cur * 16384;
    const ushort* L = H + 8192;
    const int c0 = cbase + t * 128;
    float4v acc[2][2] = {};
#pragma unroll
    for (int s = 0; s < 2; ++s) {
      short8 bh[2], bl[2];
#pragma unroll
      for (int nf = 0; nf < 2; ++nf) {
        const int row = w * 32 + nf * 16 + fm;      // local col within tile
        const int sl = (s * 4 + kq) ^ (fm & 7);
        bh[nf] = *(const short8*)(H + row * 64 + sl * 8);
        bl[nf] = *(const short8*)(L + row * 64 + sl * 8);
      }
#pragma unroll
      for (int mf = 0; mf < 2; ++mf)
#pragma unroll
        for (int nf = 0; nf < 2; ++nf) {
          acc[mf][nf] = __builtin_amdgcn_mfma_f32_16x16x32_bf16(aL[mf][s], bh[nf], acc[mf][nf], 0, 0, 0);
          acc[mf][nf] = __builtin_amdgcn_mfma_f32_16x16x32_bf16(aH[mf][s], bl[nf], acc[mf][nf], 0, 0, 0);
          acc[mf][nf] = __builtin_amdgcn_mfma_f32_16x16x32_bf16(aH[mf][s], bh[nf], acc[mf][nf], 0, 0, 0);
        }
    }
    // exp/VALU epilogue BEFORE the barrier (covers the in-flight DMAs);
    // values parked in statically-indexed regs.
    ushort ev[2][2][4];
#pragma unroll
    for (int nf = 0; nf < 2; ++nf) {
      const int col = c0 + w * 32 + nf * 16 + fm;
      const bool ok = col < NN;               // k-pad cols [5000,5120) -> exact 0
#pragma unroll
      for (int mf = 0; mf < 2; ++mf)
#pragma unroll
        for (int r = 0; r < 4; ++r) {
          const float v = fmaxf(acc[mf][nf][r], 0.f);   // relu
          const float e = ok ? __expf(v - shift[mf][r]) : 0.f;
          rs[mf][r] += e;
          ev[nf][mf][r] = f2bf(e);
        }
    }
    __builtin_amdgcn_sched_barrier(0);  // pin the exp VALU before the barrier
    if (t < 4) __syncthreads();         // drains aged DMAs + PREV tile's stores
    // stores AFTER the barrier: their drain is deferred to the next barrier.
#pragma unroll
    for (int nf = 0; nf < 2; ++nf) {
      const int col = c0 + w * 32 + nf * 16 + fm;
#pragma unroll
      for (int mf = 0; mf < 2; ++mf)
#pragma unroll
        for (int r = 0; r < 4; ++r)
          prow[mf][r][col] = ev[nf][mf][r];
    }
    cur ^= 1;
  }

  // chunk sums: shfl over the 16 fm-lanes, LDS over the 4 waves, write fp32
  // at row spare offset 9472 + 2*ch (ch = 0..7).
#pragma unroll
  for (int mf = 0; mf < 2; ++mf)
#pragma unroll
    for (int r = 0; r < 4; ++r) {
      float v = rs[mf][r];
#pragma unroll
      for (int msk = 1; msk < 16; msk <<= 1) v += __shfl_xor(v, msk);
      rs[mf][r] = v;
    }
  __syncthreads();           // redL region reuse barrier (after compute loop)
  if (fm == 0) {
#pragma unroll
    for (int mf = 0; mf < 2; ++mf)
#pragma unroll
      for (int r = 0; r < 4; ++r) redL[w][mf * 16 + kq * 4 + r] = rs[mf][r];
  }
  __syncthreads();
  if (w == 0 && fm == 0) {
#pragma unroll
    for (int mf = 0; mf < 2; ++mf)
#pragma unroll
      for (int r = 0; r < 4; ++r) {
        const int mm = mf * 16 + kq * 4 + r;
        const int gm = row0 + mm;
        if (gm < NN) {
          const float tot = redL[0][mm] + redL[1][mm] + redL[2][mm] + redL[3][mm];
          *(float*)(P + (size_t)gm * 10000 + 9472 + 2 * ch) = tot;
        }
      }
  }
}

// ---------------------------------------------------------------------------
// K3/K5: bf16 MFMA GEMM. BM=BN=128, BK=64, 256 thr = 4 waves (2x2 of 64x64,
// 32 MFMAs/wave/iter). Split-K=8 (k-chunk 640 = 10 iters), 1D grid 1280.
// R18 REVERT to the R16/R14-verified 16x16x32 version. R17's 32x32x16
// experiment: correctness exact (layout right) but SQ_LDS_BANK_CONFLICT
// 0 -> 3.28M (half-wave same-chunk reads fold 4 lanes/slot vs 16x16's free
// 2/slot) — the ~20% per-MFMA gain was consumed; dur 41.6 -> 43.4 us.
// Conflict-free 32-row-same-chunk reads are impossible under the
// global_load_lds linear-dst constraint (128B row stride = full bank wrap).
// Both in-template shape levers (BN=64 R15, 32x32 R17) now measured-refuted:
// BM=BN=128 + 16x16x32 + yb-outer decode is the optimum of this 2-phase
// structure (626 TF = template ceiling; past it = 8-phase rewrite).
// R19 (verified): YB-OUTER XCD-AWARE DECODE — yb = id>>5, xb = (id>>3)&3,
// zb = id&7 keeps XCD = zb but runs yb-major with xb inner: co-resident set
// per XCD = 16 yb x 4 xb -> A 2.6 MB + B-slice 0.65 MB < 4 MB L2.
// R13: 2-phase dbuf pipeline (stage k+1 before compute k; one barrier/iter —
// its vmcnt(0) drain is the "tile landed" wait, after the MFMAs). LDS 64 KB.
// R9 DMA locality: each wave-instr loads 8 ROWS x 128 B. Bank conflicts
// avoided by GLOBAL-side k-chunk XOR swizzle (lane fetches chunk
// slot^(row&7); frag reads slot (s*4+kq)^(fm&7)) — measured 0 conflicts.
// ---------------------------------------------------------------------------
__global__ __launch_bounds__(256) void mfma_gemm_kernel(const ushort* __restrict__ Pm,
                                                        const ushort* __restrict__ Bt,
                                                        ushort* __restrict__ Pp) {
  __shared__ __align__(16) ushort Ls[32768];  // [2 bufs][As 8192 | Bs 8192]
  const int tid = threadIdx.x;
  const int w = tid >> 6, l = tid & 63;
  const int fm = l & 15, kq = l >> 4;
  const int wm = w >> 1, wn = w & 1;
  const int id = blockIdx.x;            // 0..1279
  const int yb = id >> 5;               // row tile 0..39  (OUTER)
  const int xb = (id >> 3) & 3;         // col tile 0..3   (inner)
  const int zb = id & 7;                // k-chunk 0..7 (= XCD)
  const int row0 = yb * 128, col0 = xb * 128;
  const int kbase = zb * 640;
  // staging: call q covers rows q*32+(tid>>3), chunk slot tid&7 (XOR-swizzled)
  const int rstg = tid >> 3;            // 0..31
  const int slot = tid & 7;
  const ushort* gAq[4];
  const ushort* gBq[4];
#pragma unroll
  for (int q = 0; q < 4; ++q) {
    const int r = q * 32 + rstg;
    const int cg = slot ^ (r & 7);      // global k-chunk this lane fetches
    const int arow = row0 + r;
    gAq[q] = Pm + (size_t)arow * 10000 + (arow & 1) * 16 + kbase + cg * 8;
    gBq[q] = Bt + (size_t)(col0 + r) * KPAD + kbase + cg * 8;
  }
  ushort* lA = Ls + tid * 8;            // + buf*16384 + q*2048 (row-major exact)
  ushort* lB = Ls + 8192 + tid * 8;
  float4v acc[4][4] = {};

  auto stage = [&](int buf) {
#pragma unroll
    for (int q = 0; q < 4; ++q) gll16(gAq[q], lA + buf * 16384 + q * 2048);
#pragma unroll
    for (int q = 0; q < 4; ++q) gll16(gBq[q], lB + buf * 16384 + q * 2048);
#pragma unroll
    for (int q = 0; q < 4; ++q) { gAq[q] += 64; gBq[q] += 64; }
  };
  auto compute = [&](int buf) {
    const ushort* As = Ls + buf * 16384;
    const ushort* Bs = As + 8192;
#pragma unroll
    for (int s = 0; s < 2; ++s) {
      short8 a[4], b[4];
#pragma unroll
      for (int mt = 0; mt < 4; ++mt) {
        const int row = wm * 64 + mt * 16 + fm;
        const int sl = (s * 4 + kq) ^ (fm & 7);
        a[mt] = *(const short8*)(As + row * 64 + sl * 8);
      }
#pragma unroll
      for (int nt = 0; nt < 4; ++nt) {
        const int row = wn * 64 + nt * 16 + fm;
        const int sl = (s * 4 + kq) ^ (fm & 7);
        b[nt] = *(const short8*)(Bs + row * 64 + sl * 8);
      }
#pragma unroll
      for (int mt = 0; mt < 4; ++mt)
#pragma unroll
        for (int nt = 0; nt < 4; ++nt)
          acc[mt][nt] = __builtin_amdgcn_mfma_f32_16x16x32_bf16(a[mt], b[nt], acc[mt][nt], 0, 0, 0);
    }
  };

  stage(0);          // prologue: tile 0 -> buf 0
  __syncthreads();   // vmcnt(0) drain + barrier: buf0 ready
  int cur = 0;
  for (int kt = 0; kt < 9; ++kt) {
    stage(cur ^ 1);  // issue tile kt+1 DMAs (async, overlap with MFMAs below)
    compute(cur);
    __syncthreads(); // drains this iter's DMAs (tile kt+1 ready) + all waves
    cur ^= 1;        // done reading buf cur -> safe to overwrite next iter
  }
  compute(cur);      // last tile, no prefetch

  // epilogue: bf16 partials into the P rows' free halves
  const int cb = col0 + wn * 64 + fm;
  const int zoff = 5160 + zb * 512;
#pragma unroll
  for (int mt = 0; mt < 4; ++mt)
#pragma unroll
    for (int r = 0; r < 4; ++r) {
      const int gm = row0 + wm * 64 + mt * 16 + kq * 4 + r;
      if (gm < NN) {
        ushort* prow = Pp + (size_t)gm * 10000 + zoff + cb;
#pragma unroll
        for (int nt = 0; nt < 4; ++nt) prow[nt * 16] = f2bf(acc[mt][nt][r]);
      }
    }
}

// ---------------------------------------------------------------------------
// K4/K6: sum 8 bf16 split-K partials, SCALE by the row's deferred softmax
// inverse sum (1 / sum of the 8 fp32 chunk sums at P-row ushort offset 9472,
// two 16B-aligned float4s) -> Yf fp32 [5000][512]; optionally also Yt bf16
// [512][KPAD] (transposed, zero pad m in [5000,5120)). Grid (8,80).
// ---------------------------------------------------------------------------
__global__ __launch_bounds__(256) void reduce_kernel(const ushort* __restrict__ Pp,
                                                     float* __restrict__ Yf,
                                                     ushort* __restrict__ Yt,
                                                     int writeT) {
  const int m0 = blockIdx.y * 64, n0 = blockIdx.x * 64;
  __shared__ __align__(16) ushort Lt[64][80];  // [n][m]
  const int tid = threadIdx.x;
  const int mi = tid >> 4, nl4 = (tid & 15) << 2;
#pragma unroll
  for (int s = 0; s < 4; ++s) {
    const int m = m0 + mi + s * 16;
    float4 sum = make_float4(0.f, 0.f, 0.f, 0.f);
    if (m < NN) {
      const ushort* pr = Pp + (size_t)m * 10000 + 5160 + n0 + nl4;
#pragma unroll
      for (int z = 0; z < 8; ++z) {
        ushort4 u = *(const ushort4*)(pr + z * 512);
        sum.x += bf2f(u.x); sum.y += bf2f(u.y);
        sum.z += bf2f(u.z); sum.w += bf2f(u.w);
      }
      const float4 s4a = *(const float4*)(Pp + (size_t)m * 10000 + 9472);
      const float4 s4b = *(const float4*)(Pp + (size_t)m * 10000 + 9480);
      const float sc = 1.f / (s4a.x + s4a.y + s4a.z + s4a.w +
                              s4b.x + s4b.y + s4b.z + s4b.w);
      sum.x *= sc; sum.y *= sc; sum.z *= sc; sum.w *= sc;
      *(float4*)(Yf + (size_t)m * BC + n0 + nl4) = sum;
    }
    if (writeT) {
      const int ml = mi + s * 16;
      Lt[nl4 + 0][ml] = f2bf(sum.x);
      Lt[nl4 + 1][ml] = f2bf(sum.y);
      Lt[nl4 + 2][ml] = f2bf(sum.z);
      Lt[nl4 + 3][ml] = f2bf(sum.w);
    }
  }
  if (writeT) {
    __syncthreads();
#pragma unroll
    for (int i = 0; i < 2; ++i) {
      const int g = tid + i * 256;
      const int nl = g >> 3, gi = g & 7;
      *(uint4*)(Yt + (size_t)(n0 + nl) * KPAD + m0 + gi * 8) =
          *(const uint4*)(&Lt[nl][gi * 8]);
    }
  }
}

// ---------------------------------------------------------------------------
// K7: Wt/wwt via MFMA (R20/R21). A-frags built from the fp32 emb INPUT on
// the fly (hi/lo split, deterministic) — NOT from embH/embL, which overlay
// Y1f and are DEAD after reduce1. C[gm][col] = sum_d emb[gm][d]*wt[col][d],
// col in [0,3584): [0,3072) -> Wt (stride 3072), [3072,3584) -> wwt (512).
// Grid 157 x 14 col-chunks of 256 = 2198 blocks. B-frags direct from
// L2-resident wtH/wtL (448 KB each, untouched between prep and here).
// 48 MFMAs/block, 3-term hi/lo. Pad rows zero-guarded / store-guarded.
// ---------------------------------------------------------------------------
__global__ __launch_bounds__(256) void emb_wt_mfma_kernel(const float* __restrict__ emb,
                                                          const ushort* __restrict__ wtH,
                                                          const ushort* __restrict__ wtL,
                                                          ushort* __restrict__ Wt,
                                                          ushort* __restrict__ wwt) {
  const int tid = threadIdx.x;
  const int w = tid >> 6, l = tid & 63;
  const int fm = l & 15, kq = l >> 4;
  const int rg = blockIdx.x / 14, cc = blockIdx.x % 14;  // 157 x 14
  const int row0 = rg * 32;                   // rows 0..5023
  const int c0 = cc * 256 + w * 64;           // wave's col base in [0,3584)

  short8 aH[2][2], aL[2][2];
#pragma unroll
  for (int mf = 0; mf < 2; ++mf) {
    const int gr = row0 + mf * 16 + fm;
#pragma unroll
    for (int s = 0; s < 2; ++s) {
      short8 h = {}, lo = {};
      if (gr < NN) {
        const float* p = emb + (size_t)gr * EDIM + (s * 4 + kq) * 8;
        const float4 v0 = *(const float4*)p, v1 = *(const float4*)(p + 4);
        const float vv[8] = {v0.x, v0.y, v0.z, v0.w, v1.x, v1.y, v1.z, v1.w};
#pragma unroll
        for (int j = 0; j < 8; ++j) {
          const ushort hh = f2bf(vv[j]);
          h[j] = (short)hh;
          lo[j] = (short)f2bf(vv[j] - bf2f(hh));
        }
      }
      aH[mf][s] = h;
      aL[mf][s] = lo;
    }
  }

  float4v acc[2][4] = {};
#pragma unroll
  for (int s = 0; s < 2; ++s) {
    short8 bh[4], bl[4];
#pragma unroll
    for (int nf = 0; nf < 4; ++nf) {
      const size_t o = (size_t)(c0 + nf * 16 + fm) * 64 + (s * 4 + kq) * 8;
      bh[nf] = *(const short8*)(wtH + o);
      bl[nf] = *(const short8*)(wtL + o);
    }
#pragma unroll
    for (int mf = 0; mf < 2; ++mf)
#pragma unroll
      for (int nf = 0; nf < 4; ++nf) {
        acc[mf][nf] = __builtin_amdgcn_mfma_f32_16x16x32_bf16(aL[mf][s], bh[nf], acc[mf][nf], 0, 0, 0);
        acc[mf][nf] = __builtin_amdgcn_mfma_f32_16x16x32_bf16(aH[mf][s], bl[nf], acc[mf][nf], 0, 0, 0);
        acc[mf][nf] = __builtin_amdgcn_mfma_f32_16x16x32_bf16(aH[mf][s], bh[nf], acc[mf][nf], 0, 0, 0);
      }
  }
#pragma unroll
  for (int nf = 0; nf < 4; ++nf) {
    const int col = c0 + nf * 16 + fm;
#pragma unroll
    for (int mf = 0; mf < 2; ++mf)
#pragma unroll
      for (int r = 0; r < 4; ++r) {
        const int gm = row0 + mf * 16 + kq * 4 + r;
        if (gm < NN) {
          const ushort v = f2bf(acc[mf][nf][r]);
          if (col < 3072) Wt[(size_t)gm * 3072 + col] = v;
          else            wwt[(size_t)gm * 512 + (col - 3072)] = v;
        }
      }
  }
}

// ---------------------------------------------------------------------------
// K9: biasN fp32 [5000][64] = emb @ bias_pool.
// ---------------------------------------------------------------------------
__global__ __launch_bounds__(256) void emb_gemm_kernel(const float* __restrict__ Ae,
                                                       const float* __restrict__ Bw,
                                                       float* __restrict__ C,
                                                       int M, int Nc) {
  __shared__ float Aet[EDIM][33];
  __shared__ __align__(16) float Bs[EDIM][64];
  const int row0 = blockIdx.y * 32, col0 = blockIdx.x * 64;
  const int tid = threadIdx.x;
  for (int i = tid; i < 512; i += 256) {
    const int r = i >> 4, d4 = (i & 15) << 2;
    const int gm = row0 + r;
    float4 v = make_float4(0.f, 0.f, 0.f, 0.f);
    if (gm < M) v = *(const float4*)(Ae + (size_t)gm * EDIM + d4);
    Aet[d4 + 0][r] = v.x; Aet[d4 + 1][r] = v.y; Aet[d4 + 2][r] = v.z; Aet[d4 + 3][r] = v.w;
  }
  for (int i = tid; i < 1024; i += 256) {
    const int br = i >> 4, bc = (i & 15) << 2;
    if (bc < Nc) *(float4*)&Bs[br][bc] = *(const float4*)(Bw + (size_t)br * Nc + bc);
  }
  __syncthreads();
  const int ty = tid >> 4, tx = tid & 15;
  float acc[2][4] = {};
#pragma unroll 8
  for (int d = 0; d < EDIM; ++d) {
    const float a0 = Aet[d][ty * 2], a1 = Aet[d][ty * 2 + 1];
    const float4 b4 = *(const float4*)&Bs[d][tx << 2];
    acc[0][0] = fmaf(a0, b4.x, acc[0][0]); acc[0][1] = fmaf(a0, b4.y, acc[0][1]);
    acc[0][2] = fmaf(a0, b4.z, acc[0][2]); acc[0][3] = fmaf(a0, b4.w, acc[0][3]);
    acc[1][0] = fmaf(a1, b4.x, acc[1][0]); acc[1][1] = fmaf(a1, b4.y, acc[1][1]);
    acc[1][2] = fmaf(a1, b4.z, acc[1][2]); acc[1][3] = fmaf(a1, b4.w, acc[1][3]);
  }
#pragma unroll
  for (int r = 0; r < 2; ++r) {
    const int gm = row0 + ty * 2 + r;
    if (gm >= M) continue;
    float4 o;
    o.x = acc[r][0]; o.y = acc[r][1]; o.z = acc[r][2]; o.w = acc[r][3];
    *(float4*)(C + (size_t)gm * Nc + col0 + (tx << 2)) = o;
  }
}

// ---------------------------------------------------------------------------
// K10: xwc[b, n, i] = sum_t T[t] * x_window[b, t, n, i]
// (launched AFTER reduce2: xwc buffer overlays the dead A/P region)
// ---------------------------------------------------------------------------
__global__ __launch_bounds__(256) void window_combine_kernel(const float* __restrict__ xw,
                                                             const float* __restrict__ T,
                                                             float* __restrict__ out) {
  const int idx = blockIdx.x * 256 + threadIdx.x;
  if (idx >= BB * NN * 16) return;
  const int b = idx / (NN * 16);
  const int rem = idx - b * (NN * 16);
  float acc = 0.f;
#pragma unroll
  for (int t = 0; t < LAGN; ++t)
    acc = fmaf(T[t], xw[(size_t)(b * LAGN + t) * (NN * 16) + rem], acc);
  out[idx] = acc;
}

// ---------------------------------------------------------------------------
// K11: MFMA fusion. One wave per node: gconv (6 MFMAs) + wconv (2 MFMAs),
// LN via 16-lane butterflies on the C-layout, concat + bias.
// ---------------------------------------------------------------------------
__global__ __launch_bounds__(256) void fuse_mfma_kernel(const float* __restrict__ x,
                                                        const float* __restrict__ Y1f,
                                                        const float* __restrict__ Y2f,
                                                        const ushort* __restrict__ Wt,
                                                        const ushort* __restrict__ wwt,
                                                        const float* __restrict__ biasN,
                                                        const float* __restrict__ xwc,
                                                        const float* __restrict__ ln1w,
                                                        const float* __restrict__ ln1b,
                                                        const float* __restrict__ ln2w,
                                                        const float* __restrict__ ln2b,
                                                        float* __restrict__ out) {
  const int tid = threadIdx.x;
  const int n = blockIdx.x * 4 + (tid >> 6);  // grid 1250*4 = 5000 exact
  const int l = tid & 63, fm = l & 15, kq = l >> 4;
  const short8 ax = cvt8(x + ((size_t)fm * NN + n) * DINC + kq * 8);
  const short8 a1 = cvt8(Y1f + (size_t)n * BC + fm * 32 + kq * 8);
  const short8 a2 = cvt8(Y2f + (size_t)n * BC + fm * 32 + kq * 8);
  short8 aw = {};
  if (kq < 2) aw = cvt8(xwc + ((size_t)fm * NN + n) * 16 + kq * 8);
  const ushort* wn = Wt + (size_t)n * 3072;
  const ushort* wwn = wwt + (size_t)n * 512;
  float4v accG[2] = {}, accW[2] = {};
#pragma unroll
  for (int t = 0; t < 2; ++t) {
    const int ob = (t * 16 + fm) * 96 + kq * 8;
    const short8 b0 = *(const short8*)(wn + ob);
    const short8 b1 = *(const short8*)(wn + ob + 32);
    const short8 b2 = *(const short8*)(wn + ob + 64);
    accG[t] = __builtin_amdgcn_mfma_f32_16x16x32_bf16(ax, b0, accG[t], 0, 0, 0);
    accG[t] = __builtin_amdgcn_mfma_f32_16x16x32_bf16(a1, b1, accG[t], 0, 0, 0);
    accG[t] = __builtin_amdgcn_mfma_f32_16x16x32_bf16(a2, b2, accG[t], 0, 0, 0);
    short8 bw = {};
    if (kq < 2) bw = *(const short8*)(wwn + (t * 16 + fm) * 16 + kq * 8);
    accW[t] = __builtin_amdgcn_mfma_f32_16x16x32_bf16(aw, bw, accW[t], 0, 0, 0);
  }
  const float w1a = ln1w[fm], w1b = ln1w[16 + fm];
  const float c1a = ln1b[fm], c1b = ln1b[16 + fm];
  const float w2a = ln2w[fm], w2b = ln2w[16 + fm];
  const float c2a = ln2b[fm], c2b = ln2b[16 + fm];
  const float* bn = biasN + (size_t)n * 64;
  const float bga = bn[fm], bgb = bn[16 + fm];
  const float bwa = bn[32 + fm], bwb = bn[48 + fm];
#pragma unroll
  for (int r = 0; r < 4; ++r) {
    const int b = kq * 4 + r;
    const float g0 = accG[0][r], g1 = accG[1][r];
    float s1 = g0 + g1, s2 = g0 * g0 + g1 * g1;
#pragma unroll
    for (int m = 1; m < 16; m <<= 1) { s1 += __shfl_xor(s1, m); s2 += __shfl_xor(s2, m); }
    const float mu = s1 * 0.03125f;
    const float rs = rsqrtf(s2 * 0.03125f - mu * mu + 1e-5f);
    const float h0 = accW[0][r], h1 = accW[1][r];
    float t1 = h0 + h1, t2 = h0 * h0 + h1 * h1;
#pragma unroll
    for (int m = 1; m < 16; m <<= 1) { t1 += __shfl_xor(t1, m); t2 += __shfl_xor(t2, m); }
    const float mu2 = t1 * 0.03125f;
    const float rs2 = rsqrtf(t2 * 0.03125f - mu2 * mu2 + 1e-5f);
    float* op = out + ((size_t)b * NN + n) * 64;
    op[fm]      = (g0 - mu) * rs * w1a + c1a + bga;
    op[16 + fm] = (g1 - mu) * rs * w1b + c1b + bgb;
    op[32 + fm] = (h0 - mu2) * rs2 * w2a + c2a + bwa;
    op[48 + fm] = (h1 - mu2) * rs2 * w2b + c2b + bwb;
  }
}

// ---------------------------------------------------------------------------
// Workspace map (fp32 slots), high-water 30,410,816 floats = 121.6 MB:
//   [0, 25M)              P bf16 rows (fused_A_softmax output; row m =
//                         ushorts [m*10000+(m&1)*16, +5120) P~,
//                         [m*10000+5160, +4096) 8 bf16 split-K partial slabs,
//                         chunk sums fp32[8] at ushort offset m*10000+9472)
//                         -> after reduce2: overlaid by Wt/wwt/biasN/xwc
//   [25.0M, 26.31072M)    XbT bf16 [512][5120]   (dead after GEMM1)
//   [26.31072M,27.62144M) Y1t bf16 [512][5120]   (dead after GEMM2)
//   [25.0M, 27.56M)       Y2f fp32 (reduce2 output, overlays XbT+Y1t)
//   [27.62144M,30.18144M) Y1f fp32; BEFORE reduce1 this region also hosts:
//       [27621440,27785280)  embH bf16 [5120][64]  (DEAD after reduce1! —
//       [27785280,27949120)  embL bf16 [5120][64]   only fused_A may read)
//       [27949120,27951680)  ascr — 5120-ushort tail-row store scratch
//   [30181440,30296128)   wtH bf16 [3584][64] (transposed hi pools; live
//   [30296128,30410816)   wtL bf16 [3584][64]  from prep to emb_wt_mfma)
// ---------------------------------------------------------------------------
extern "C" void kernel_launch(void* const* d_in, const int* in_sizes, int n_in,
                              void* d_out, int out_size, void* d_ws, size_t ws_size,
                              hipStream_t stream) {
  const float* x     = (const float*)d_in[0];
  const float* xwin  = (const float*)d_in[1];
  const float* emb   = (const float*)d_in[2];
  const float* wpool = (const float*)d_in[3];
  const float* wwin  = (const float*)d_in[4];
  const float* bpool = (const float*)d_in[5];
  const float* T     = (const float*)d_in[6];
  const float* ln1w  = (const float*)d_in[7];
  const float* ln1b  = (const float*)d_in[8];
  const float* ln2w  = (const float*)d_in[9];
  const float* ln2b  = (const float*)d_in[10];
  float* out = (float*)d_out;
  float* ws = (float*)d_ws;

  ushort* P    = (ushort*)ws;
  ushort* XbT  = (ushort*)(ws + 25000000);
  ushort* Y1t  = (ushort*)(ws + 26310720);
  float*  Y1f  = ws + 27621440;
  float*  Y2f  = ws + 25000000;        // overlays XbT+Y1t after GEMM2
  ushort* embH = (ushort*)(ws + 27621440);   // overlays Y1f until reduce1
  ushort* embL = (ushort*)(ws + 27785280);
  ushort* ascr = (ushort*)(ws + 27949120);   // 5120-ushort tail scratch
  ushort* Wt    = (ushort*)ws;         // [5000][3072] bf16, overlays P after reduce2
  ushort* wwt   = (ushort*)(ws + 15360000);  // [5000][512] bf16
  float*  biasN = ws + 17920000;
  float*  xwc   = ws + 18240000;       // overlays P rows — write after reduce2!
  ushort* wtH   = (ushort*)(ws + 30181440);  // [3584][64] bf16 hi
  ushort* wtL   = (ushort*)(ws + 30296128);  // [3584][64] bf16 lo

  prep_kernel<<<12416, 256, 0, stream>>>(x, wpool, wwin, emb, XbT, wtH, wtL, embH, embL);
  fused_A_softmax_kernel<<<1256, 256, 0, stream>>>(embH, embL, P, ascr);
  mfma_gemm_kernel<<<1280, 256, 0, stream>>>(P, XbT, P);
  reduce_kernel<<<dim3(8, 80), 256, 0, stream>>>(P, Y1f, Y1t, 1);
  mfma_gemm_kernel<<<1280, 256, 0, stream>>>(P, Y1t, P);
  reduce_kernel<<<dim3(8, 80), 256, 0, stream>>>(P, Y2f, (ushort*)nullptr, 0);
  emb_wt_mfma_kernel<<<2198, 256, 0, stream>>>(emb, wtH, wtL, Wt, wwt);
  emb_gemm_kernel<<<dim3(1, 157), 256, 0, stream>>>(emb, bpool, biasN, NN, 64);
  window_combine_kernel<<<(BB * NN * 16 + 255) / 256, 256, 0, stream>>>(xwin, T, xwc);
  fuse_mfma_kernel<<<1250, 256, 0, stream>>>(x, Y1f, Y2f, Wt, wwt, biasN, xwc,
                                             ln1w, ln1b, ln2w, ln2b, out);
}